// Round 5
// baseline (268.335 us; speedup 1.0000x reference)
//
#include <hip/hip_runtime.h>
#include <hip/hip_bf16.h>
#include <limits.h>
#include <math.h>

#define N 50000
#define E_ 800000
#define ETOT 850000          // E + N self loops
#define HH 128               // HEADS*HID
#define HEADS 8
#define HID 16
#define CLS 16
#define NEG 0.2f
#define NB ((N + 255) / 256) // 196 scan blocks

// ---------------- CSR build ----------------
__global__ __launch_bounds__(256) void k_zero(int* __restrict__ deg){
  int i = blockIdx.x*256 + threadIdx.x;
  if(i < N) deg[i] = 0;
}

__global__ __launch_bounds__(256) void k_hist(const int* __restrict__ ei, int* __restrict__ deg){
  int e = blockIdx.x*256 + threadIdx.x;
  if(e >= ETOT) return;
  int d = (e < E_) ? ei[E_ + e] : e - E_;
  atomicAdd(&deg[d], 1);
}

__global__ __launch_bounds__(256) void k_scan1(const int* __restrict__ deg, int* __restrict__ bsum){
  __shared__ int sm[256];
  int t = threadIdx.x;
  int i = blockIdx.x*256 + t;
  sm[t] = (i < N) ? deg[i] : 0;
  __syncthreads();
  #pragma unroll
  for(int ofs=128; ofs>0; ofs>>=1){
    if(t < ofs) sm[t] += sm[t+ofs];
    __syncthreads();
  }
  if(t == 0) bsum[blockIdx.x] = sm[0];
}

__global__ __launch_bounds__(256) void k_scan2(const int* __restrict__ bsum,
                                               int* __restrict__ boff,
                                               int* __restrict__ off){
  __shared__ int sm[256];
  int t = threadIdx.x;
  sm[t] = (t < NB) ? bsum[t] : 0;
  __syncthreads();
  #pragma unroll
  for(int ofs=1; ofs<256; ofs<<=1){
    int v = sm[t];
    int add = (t >= ofs) ? sm[t-ofs] : 0;
    __syncthreads();
    sm[t] = v + add;
    __syncthreads();
  }
  if(t < NB) boff[t] = (t == 0) ? 0 : sm[t-1];
  if(t == 255) off[N] = sm[NB-1];
}

__global__ __launch_bounds__(256) void k_scan3(const int* __restrict__ deg,
                                               const int* __restrict__ boff,
                                               int* __restrict__ off,
                                               int* __restrict__ cursor){
  __shared__ int sm[256];
  int t = threadIdx.x;
  int i = blockIdx.x*256 + t;
  int v0 = (i < N) ? deg[i] : 0;
  sm[t] = v0;
  __syncthreads();
  #pragma unroll
  for(int ofs=1; ofs<256; ofs<<=1){
    int v = sm[t];
    int add = (t >= ofs) ? sm[t-ofs] : 0;
    __syncthreads();
    sm[t] = v + add;
    __syncthreads();
  }
  if(i < N){
    int excl = boff[blockIdx.x] + sm[t] - v0;
    off[i] = excl;
    cursor[i] = excl;
  }
}

__global__ __launch_bounds__(256) void k_fill(const int* __restrict__ ei,
                                              int* __restrict__ cursor,
                                              int* __restrict__ csr_src){
  int e = blockIdx.x*256 + threadIdx.x;
  if(e >= ETOT) return;
  int s, d;
  if(e < E_){ s = ei[e]; d = ei[E_ + e]; } else { s = d = e - E_; }
  int pos = atomicAdd(&cursor[d], 1);
  csr_src[pos] = s;
}

// ---------------- GEMM1 + fused alpha1 epilogue ----------------
#define BM 64
#define BKK 32
__global__ __launch_bounds__(256) void k_gemm1(const float* __restrict__ x,
                                               const float* __restrict__ W,
                                               const float* __restrict__ Asv,
                                               const float* __restrict__ Adv,
                                               float* __restrict__ h1,
                                               float* __restrict__ as1,
                                               float* __restrict__ ad1){
  __shared__ float xT[BKK*BM];      // 8 KiB
  __shared__ float Wl[BKK*128];     // 16 KiB, xor-swizzled
  int tid = threadIdx.x;
  int row0 = blockIdx.x * BM;
  int tx = tid & 15;
  int ty = tid >> 4;
  float acc[4][8];
  #pragma unroll
  for(int r=0;r<4;r++)
    #pragma unroll
    for(int j=0;j<8;j++) acc[r][j]=0.f;

  int lr = tid >> 2;
  int lk = (tid & 3) * 8;
  int wr = tid >> 3;
  int wc = (tid & 7) * 16;
  int xrow = row0 + lr; if(xrow >= N) xrow = N-1;
  const float* xbase = x + (size_t)xrow*128;

  for(int k0=0; k0<128; k0+=BKK){
    float4 v0 = *(const float4*)(xbase + k0 + lk);
    float4 v1 = *(const float4*)(xbase + k0 + lk + 4);
    float4 wv0, wv1, wv2, wv3;
    {
      const float4* wsrc = (const float4*)(W + (size_t)(k0+wr)*128 + wc);
      wv0 = wsrc[0]; wv1 = wsrc[1]; wv2 = wsrc[2]; wv3 = wsrc[3];
    }
    __syncthreads();
    xT[(lk+0)*BM + lr] = v0.x;
    xT[(lk+1)*BM + lr] = v0.y;
    xT[(lk+2)*BM + lr] = v0.z;
    xT[(lk+3)*BM + lr] = v0.w;
    xT[(lk+4)*BM + lr] = v1.x;
    xT[(lk+5)*BM + lr] = v1.y;
    xT[(lk+6)*BM + lr] = v1.z;
    xT[(lk+7)*BM + lr] = v1.w;
    {
      char* wl = (char*)Wl;
      int swz = (wr & 7) << 4;
      int b = (wr*128 + wc)*4;
      *(float4*)(wl + ((b      ) ^ swz)) = wv0;
      *(float4*)(wl + ((b + 16 ) ^ swz)) = wv1;
      *(float4*)(wl + ((b + 32 ) ^ swz)) = wv2;
      *(float4*)(wl + ((b + 48 ) ^ swz)) = wv3;
    }
    __syncthreads();
    #pragma unroll 8
    for(int k=0;k<BKK;k++){
      float4 xv = *(const float4*)&xT[k*BM + ty*4];
      const char* wl = (const char*)Wl;
      int swz = (k & 7) << 4;
      float4 wa = *(const float4*)(wl + ((k*512 + tx*16      ) ^ swz));
      float4 wb = *(const float4*)(wl + ((k*512 + 256 + tx*16) ^ swz));
      float xr[4] = {xv.x, xv.y, xv.z, xv.w};
      #pragma unroll
      for(int r=0;r<4;r++){
        acc[r][0] = fmaf(xr[r], wa.x, acc[r][0]);
        acc[r][1] = fmaf(xr[r], wa.y, acc[r][1]);
        acc[r][2] = fmaf(xr[r], wa.z, acc[r][2]);
        acc[r][3] = fmaf(xr[r], wa.w, acc[r][3]);
        acc[r][4] = fmaf(xr[r], wb.x, acc[r][4]);
        acc[r][5] = fmaf(xr[r], wb.y, acc[r][5]);
        acc[r][6] = fmaf(xr[r], wb.z, acc[r][6]);
        acc[r][7] = fmaf(xr[r], wb.w, acc[r][7]);
      }
    }
  }
  // att weights for this thread's 8 columns (lower: cols tx*4.., upper: 64+tx*4..)
  float as_lo[4], as_hi[4], ad_lo[4], ad_hi[4];
  #pragma unroll
  for(int j=0;j<4;j++){
    as_lo[j] = Asv[tx*4+j];      ad_lo[j] = Adv[tx*4+j];
    as_hi[j] = Asv[64+tx*4+j];   ad_hi[j] = Adv[64+tx*4+j];
  }
  int q = tx >> 2;
  #pragma unroll
  for(int r=0;r<4;r++){
    int row = row0 + ty*4 + r;
    float ps_lo=0.f, ps_hi=0.f, pd_lo=0.f, pd_hi=0.f;
    #pragma unroll
    for(int j=0;j<4;j++){
      ps_lo = fmaf(acc[r][j],   as_lo[j], ps_lo);
      pd_lo = fmaf(acc[r][j],   ad_lo[j], pd_lo);
      ps_hi = fmaf(acc[r][4+j], as_hi[j], ps_hi);
      pd_hi = fmaf(acc[r][4+j], ad_hi[j], pd_hi);
    }
    ps_lo += __shfl_xor(ps_lo,1); ps_lo += __shfl_xor(ps_lo,2);
    pd_lo += __shfl_xor(pd_lo,1); pd_lo += __shfl_xor(pd_lo,2);
    ps_hi += __shfl_xor(ps_hi,1); ps_hi += __shfl_xor(ps_hi,2);
    pd_hi += __shfl_xor(pd_hi,1); pd_hi += __shfl_xor(pd_hi,2);
    if(row < N){
      float* dst = h1 + (size_t)row*128;
      *(float4*)(dst + tx*4)      = make_float4(acc[r][0],acc[r][1],acc[r][2],acc[r][3]);
      *(float4*)(dst + 64 + tx*4) = make_float4(acc[r][4],acc[r][5],acc[r][6],acc[r][7]);
      if((tx & 3) == 0){
        as1[row*8 + q]     = ps_lo;  as1[row*8 + 4 + q] = ps_hi;
        ad1[row*8 + q]     = pd_lo;  ad1[row*8 + 4 + q] = pd_hi;
      }
    }
  }
}

// ---------------- per-(node,head) softmax max, layer 1 ----------------
// m = leaky(max_e as1[s,h] + ad1[node,h])  (leaky monotone, ad const per node)
__global__ __launch_bounds__(256) void k_max1(const int* __restrict__ off,
                                              const int* __restrict__ csr,
                                              const float* __restrict__ as1,
                                              const float* __restrict__ ad1,
                                              float* __restrict__ mfin){
  int id = blockIdx.x*256 + threadIdx.x;
  if(id >= N*HEADS) return;
  int node = id >> 3, h = id & 7;
  int beg = off[node], end = off[node+1];
  float m = -INFINITY;
  for(int e=beg; e<end; e++){
    int s = csr[e];
    m = fmaxf(m, as1[s*8 + h]);
  }
  float v = m + ad1[id];
  mfin[id] = v > 0.f ? v : NEG*v;
}

// ---------------- fused layer-1 aggregation (shared-exp via LDS) ----------------
#define CH 32
__global__ __launch_bounds__(128) void k_agg1(const int* __restrict__ off,
                                              const int* __restrict__ csr,
                                              const float* __restrict__ as1,
                                              const float* __restrict__ ad1,
                                              const float* __restrict__ mfin,
                                              const float* __restrict__ h1,
                                              const float* __restrict__ b1,
                                              float* __restrict__ helu){
  __shared__ float wsm[CH*8];
  __shared__ int   ssm[CH];
  int node = blockIdx.x;
  int c = threadIdx.x;          // 0..127
  int h = c >> 4;               // head for phase B
  int beg = off[node], end = off[node+1];
  // phase-A identity: thread covers edges (c>>3) and (c>>3)+16 for head (c&7)
  int el = c >> 3, hh = c & 7;
  float advA = ad1[node*8 + hh];
  float mA   = mfin[node*8 + hh];
  float mB   = mfin[node*8 + h];
  float den = 0.f, num = 0.f;
  for(int base = beg; base < end; base += CH){
    int cnt = end - base; if(cnt > CH) cnt = CH;
    __syncthreads();                       // previous chunk's reads done
    #pragma unroll
    for(int k=0; k<CH; k+=16){
      int e = el + k;
      if(e < cnt){
        int s = csr[base + e];
        if(hh == 0) ssm[e] = s;
        float v = as1[s*8 + hh] + advA;
        v = v > 0.f ? v : NEG*v;
        wsm[e*8 + hh] = __expf(v - mA);
      }
    }
    __syncthreads();
    for(int e=0; e<cnt; e++){
      int s  = ssm[e];
      float w = wsm[e*8 + h];
      float xx = h1[(size_t)s*HH + c];
      den += w;
      num = fmaf(w, xx, num);
    }
  }
  (void)mB;
  float res = num / (den + 1e-16f) + b1[c];
  helu[(size_t)node*HH + c] = res > 0.f ? res : expm1f(res);
}

// ---------------- GEMM2 + fused alpha2 ----------------
__global__ __launch_bounds__(256) void k_gemm2(const float* __restrict__ h,
                                               const float* __restrict__ W2,
                                               const float* __restrict__ Asv,
                                               const float* __restrict__ Adv,
                                               float* __restrict__ h2,
                                               float* __restrict__ as2,
                                               float* __restrict__ ad2){
  __shared__ float Wl[128*16];
  int tid = threadIdx.x;
  const float4* W4 = (const float4*)W2;
  float4* Wl4 = (float4*)Wl;
  Wl4[tid]       = W4[tid];
  Wl4[tid + 256] = W4[tid + 256];
  __syncthreads();
  int i = blockIdx.x*16 + (tid >> 4);
  int c = tid & 15;
  if(i >= N) return;
  const float4* h4 = (const float4*)(h + (size_t)i*HH);
  float acc = 0.f;
  #pragma unroll
  for(int k4=0;k4<32;k4++){
    float4 v = h4[k4];
    acc = fmaf(v.x, Wl[(4*k4+0)*16+c], acc);
    acc = fmaf(v.y, Wl[(4*k4+1)*16+c], acc);
    acc = fmaf(v.z, Wl[(4*k4+2)*16+c], acc);
    acc = fmaf(v.w, Wl[(4*k4+3)*16+c], acc);
  }
  h2[(size_t)i*CLS + c] = acc;
  float ps = acc * Asv[c];
  float pd = acc * Adv[c];
  ps += __shfl_xor(ps,1); ps += __shfl_xor(ps,2); ps += __shfl_xor(ps,4); ps += __shfl_xor(ps,8);
  pd += __shfl_xor(pd,1); pd += __shfl_xor(pd,2); pd += __shfl_xor(pd,4); pd += __shfl_xor(pd,8);
  if(c == 0){ as2[i] = ps; ad2[i] = pd; }
}

// ---------------- per-node softmax max, layer 2 ----------------
__global__ __launch_bounds__(256) void k_max2(const int* __restrict__ off,
                                              const int* __restrict__ csr,
                                              const float* __restrict__ as2,
                                              const float* __restrict__ ad2,
                                              float* __restrict__ mfin){
  int node = blockIdx.x*256 + threadIdx.x;
  if(node >= N) return;
  int beg = off[node], end = off[node+1];
  float m = -INFINITY;
  for(int e=beg; e<end; e++) m = fmaxf(m, as2[csr[e]]);
  float v = m + ad2[node];
  mfin[node] = v > 0.f ? v : NEG*v;
}

// ---------------- fused layer-2 aggregation + final bias ----------------
__global__ __launch_bounds__(256) void k_agg2(const int* __restrict__ off,
                                              const int* __restrict__ csr,
                                              const float* __restrict__ as2,
                                              const float* __restrict__ ad2,
                                              const float* __restrict__ mfin,
                                              const float* __restrict__ h2,
                                              const float* __restrict__ b2,
                                              float* __restrict__ outp){
  int node = blockIdx.x*16 + (threadIdx.x >> 4);
  int c = threadIdx.x & 15;
  if(node >= N) return;
  int beg = off[node], end = off[node+1];
  float adv = ad2[node];
  float m = mfin[node];
  float den = 0.f, num = 0.f;
  int e = beg;
  for(; e + 2 <= end; e += 2){
    int s0 = csr[e], s1 = csr[e+1];
    float v0 = as2[s0] + adv, v1 = as2[s1] + adv;
    v0 = v0 > 0.f ? v0 : NEG*v0;
    v1 = v1 > 0.f ? v1 : NEG*v1;
    float w0 = __expf(v0 - m), w1 = __expf(v1 - m);
    float x0 = h2[(size_t)s0*CLS + c], x1 = h2[(size_t)s1*CLS + c];
    den += w0 + w1;
    num = fmaf(w0, x0, num);
    num = fmaf(w1, x1, num);
  }
  for(; e < end; e++){
    int s = csr[e];
    float v = as2[s] + adv;
    v = v > 0.f ? v : NEG*v;
    float w = __expf(v - m);
    den += w;
    num = fmaf(w, h2[(size_t)s*CLS + c], num);
  }
  outp[(size_t)node*CLS + c] = num / (den + 1e-16f) + b2[c];
}

extern "C" void kernel_launch(void* const* d_in, const int* in_sizes, int n_in,
                              void* d_out, int out_size, void* d_ws, size_t ws_size,
                              hipStream_t stream){
  const float* x     = (const float*)d_in[0];
  const int*   ei    = (const int*)  d_in[1];
  const float* W1    = (const float*)d_in[2];
  const float* av_s1 = (const float*)d_in[3];
  const float* av_d1 = (const float*)d_in[4];
  const float* b1    = (const float*)d_in[5];
  const float* W2    = (const float*)d_in[6];
  const float* av_s2 = (const float*)d_in[7];
  const float* av_d2 = (const float*)d_in[8];
  const float* b2    = (const float*)d_in[9];
  float* outp = (float*)d_out;

  char* p = (char*)d_ws;
  auto alloc = [&](size_t bytes){ char* q = p; p += (bytes + 255) & ~(size_t)255; return q; };
  float* h1     = (float*)alloc((size_t)N*HH*4);
  float* helu   = (float*)alloc((size_t)N*HH*4);
  float* as1    = (float*)alloc((size_t)N*HEADS*4);
  float* ad1    = (float*)alloc((size_t)N*HEADS*4);
  float* mfin1  = (float*)alloc((size_t)N*HEADS*4);
  float* h2     = (float*)alloc((size_t)N*CLS*4);
  float* as2    = (float*)alloc((size_t)N*4);
  float* ad2    = (float*)alloc((size_t)N*4);
  float* mfin2  = (float*)alloc((size_t)N*4);
  int*   deg    = (int*)  alloc((size_t)N*4);
  int*   off    = (int*)  alloc((size_t)(N+1)*4);
  int*   cursor = (int*)  alloc((size_t)N*4);
  int*   csr    = (int*)  alloc((size_t)ETOT*4);
  int*   bsum   = (int*)  alloc((size_t)NB*4);
  int*   boff   = (int*)  alloc((size_t)NB*4);

  // CSR build (shared by both layers)
  k_zero<<<(N+255)/256, 256, 0, stream>>>(deg);
  k_hist<<<(ETOT+255)/256, 256, 0, stream>>>(ei, deg);
  k_scan1<<<NB, 256, 0, stream>>>(deg, bsum);
  k_scan2<<<1, 256, 0, stream>>>(bsum, boff, off);
  k_scan3<<<NB, 256, 0, stream>>>(deg, boff, off, cursor);
  k_fill<<<(ETOT+255)/256, 256, 0, stream>>>(ei, cursor, csr);

  // layer 1
  k_gemm1<<<(N+BM-1)/BM, 256, 0, stream>>>(x, W1, av_s1, av_d1, h1, as1, ad1);
  k_max1<<<(N*HEADS+255)/256, 256, 0, stream>>>(off, csr, as1, ad1, mfin1);
  k_agg1<<<N, 128, 0, stream>>>(off, csr, as1, ad1, mfin1, h1, b1, helu);

  // layer 2
  k_gemm2<<<(N+15)/16, 256, 0, stream>>>(helu, W2, av_s2, av_d2, h2, as2, ad2);
  k_max2<<<(N+255)/256, 256, 0, stream>>>(off, csr, as2, ad2, mfin2);
  k_agg2<<<(N+15)/16, 256, 0, stream>>>(off, csr, as2, ad2, mfin2, h2, b2, outp);
}

// Round 6
// 220.026 us; speedup vs baseline: 1.2196x; 1.2196x over previous
//
#include <hip/hip_runtime.h>
#include <hip/hip_bf16.h>
#include <limits.h>
#include <math.h>

#define N 50000
#define E_ 800000
#define ETOT 850000          // E + N self loops
#define HH 128               // HEADS*HID
#define HEADS 8
#define HID 16
#define CLS 16
#define NEG 0.2f
#define NB ((N + 255) / 256) // 196 scan blocks

typedef unsigned short u16;
typedef unsigned int   u32;

__device__ __forceinline__ u16 f2bu(float f){           // f32 -> bf16 RNE
  union{float f; u32 i;} c; c.f = f;
  u32 lsb = (c.i >> 16) & 1u;
  c.i += 0x7fffu + lsb;
  return (u16)(c.i >> 16);
}
__device__ __forceinline__ float bu2f(u16 u){           // bf16 -> f32
  union{u32 i; float f;} c; c.i = ((u32)u) << 16; return c.f;
}
__device__ __forceinline__ float blo(u32 u){ union{u32 i; float f;} c; c.i = u << 16; return c.f; }
__device__ __forceinline__ float bhi(u32 u){ union{u32 i; float f;} c; c.i = u & 0xffff0000u; return c.f; }

// ---------------- CSR build ----------------
__global__ __launch_bounds__(256) void k_zero(int* __restrict__ deg){
  int i = blockIdx.x*256 + threadIdx.x;
  if(i < N) deg[i] = 0;
}

__global__ __launch_bounds__(256) void k_hist(const int* __restrict__ ei, int* __restrict__ deg){
  int e = blockIdx.x*256 + threadIdx.x;
  if(e >= ETOT) return;
  int d = (e < E_) ? ei[E_ + e] : e - E_;
  atomicAdd(&deg[d], 1);
}

__global__ __launch_bounds__(256) void k_scan1(const int* __restrict__ deg, int* __restrict__ bsum){
  __shared__ int sm[256];
  int t = threadIdx.x;
  int i = blockIdx.x*256 + t;
  sm[t] = (i < N) ? deg[i] : 0;
  __syncthreads();
  #pragma unroll
  for(int ofs=128; ofs>0; ofs>>=1){
    if(t < ofs) sm[t] += sm[t+ofs];
    __syncthreads();
  }
  if(t == 0) bsum[blockIdx.x] = sm[0];
}

__global__ __launch_bounds__(256) void k_scan2(const int* __restrict__ bsum,
                                               int* __restrict__ boff,
                                               int* __restrict__ off){
  __shared__ int sm[256];
  int t = threadIdx.x;
  sm[t] = (t < NB) ? bsum[t] : 0;
  __syncthreads();
  #pragma unroll
  for(int ofs=1; ofs<256; ofs<<=1){
    int v = sm[t];
    int add = (t >= ofs) ? sm[t-ofs] : 0;
    __syncthreads();
    sm[t] = v + add;
    __syncthreads();
  }
  if(t < NB) boff[t] = (t == 0) ? 0 : sm[t-1];
  if(t == 255) off[N] = sm[NB-1];
}

__global__ __launch_bounds__(256) void k_scan3(const int* __restrict__ deg,
                                               const int* __restrict__ boff,
                                               int* __restrict__ off,
                                               int* __restrict__ cursor){
  __shared__ int sm[256];
  int t = threadIdx.x;
  int i = blockIdx.x*256 + t;
  int v0 = (i < N) ? deg[i] : 0;
  sm[t] = v0;
  __syncthreads();
  #pragma unroll
  for(int ofs=1; ofs<256; ofs<<=1){
    int v = sm[t];
    int add = (t >= ofs) ? sm[t-ofs] : 0;
    __syncthreads();
    sm[t] = v + add;
    __syncthreads();
  }
  if(i < N){
    int excl = boff[blockIdx.x] + sm[t] - v0;
    off[i] = excl;
    cursor[i] = excl;
  }
}

__global__ __launch_bounds__(256) void k_fill(const int* __restrict__ ei,
                                              int* __restrict__ cursor,
                                              int* __restrict__ csr_src){
  int e = blockIdx.x*256 + threadIdx.x;
  if(e >= ETOT) return;
  int s, d;
  if(e < E_){ s = ei[e]; d = ei[E_ + e]; } else { s = d = e - E_; }
  int pos = atomicAdd(&cursor[d], 1);
  csr_src[pos] = s;
}

// ---------------- GEMM1 + fused alpha1 epilogue; h1 stored bf16 ----------------
#define BM 64
#define BKK 32
__global__ __launch_bounds__(256) void k_gemm1(const float* __restrict__ x,
                                               const float* __restrict__ W,
                                               const float* __restrict__ Asv,
                                               const float* __restrict__ Adv,
                                               u16* __restrict__ h1b,
                                               float* __restrict__ as1,
                                               float* __restrict__ ad1){
  __shared__ float xT[BKK*BM];      // 8 KiB
  __shared__ float Wl[BKK*128];     // 16 KiB, xor-swizzled
  int tid = threadIdx.x;
  int row0 = blockIdx.x * BM;
  int tx = tid & 15;
  int ty = tid >> 4;
  float acc[4][8];
  #pragma unroll
  for(int r=0;r<4;r++)
    #pragma unroll
    for(int j=0;j<8;j++) acc[r][j]=0.f;

  int lr = tid >> 2;
  int lk = (tid & 3) * 8;
  int wr = tid >> 3;
  int wc = (tid & 7) * 16;
  int xrow = row0 + lr; if(xrow >= N) xrow = N-1;
  const float* xbase = x + (size_t)xrow*128;

  for(int k0=0; k0<128; k0+=BKK){
    float4 v0 = *(const float4*)(xbase + k0 + lk);
    float4 v1 = *(const float4*)(xbase + k0 + lk + 4);
    float4 wv0, wv1, wv2, wv3;
    {
      const float4* wsrc = (const float4*)(W + (size_t)(k0+wr)*128 + wc);
      wv0 = wsrc[0]; wv1 = wsrc[1]; wv2 = wsrc[2]; wv3 = wsrc[3];
    }
    __syncthreads();
    xT[(lk+0)*BM + lr] = v0.x;
    xT[(lk+1)*BM + lr] = v0.y;
    xT[(lk+2)*BM + lr] = v0.z;
    xT[(lk+3)*BM + lr] = v0.w;
    xT[(lk+4)*BM + lr] = v1.x;
    xT[(lk+5)*BM + lr] = v1.y;
    xT[(lk+6)*BM + lr] = v1.z;
    xT[(lk+7)*BM + lr] = v1.w;
    {
      char* wl = (char*)Wl;
      int swz = (wr & 7) << 4;
      int b = (wr*128 + wc)*4;
      *(float4*)(wl + ((b      ) ^ swz)) = wv0;
      *(float4*)(wl + ((b + 16 ) ^ swz)) = wv1;
      *(float4*)(wl + ((b + 32 ) ^ swz)) = wv2;
      *(float4*)(wl + ((b + 48 ) ^ swz)) = wv3;
    }
    __syncthreads();
    #pragma unroll 8
    for(int k=0;k<BKK;k++){
      float4 xv = *(const float4*)&xT[k*BM + ty*4];
      const char* wl = (const char*)Wl;
      int swz = (k & 7) << 4;
      float4 wa = *(const float4*)(wl + ((k*512 + tx*16      ) ^ swz));
      float4 wb = *(const float4*)(wl + ((k*512 + 256 + tx*16) ^ swz));
      float xr[4] = {xv.x, xv.y, xv.z, xv.w};
      #pragma unroll
      for(int r=0;r<4;r++){
        acc[r][0] = fmaf(xr[r], wa.x, acc[r][0]);
        acc[r][1] = fmaf(xr[r], wa.y, acc[r][1]);
        acc[r][2] = fmaf(xr[r], wa.z, acc[r][2]);
        acc[r][3] = fmaf(xr[r], wa.w, acc[r][3]);
        acc[r][4] = fmaf(xr[r], wb.x, acc[r][4]);
        acc[r][5] = fmaf(xr[r], wb.y, acc[r][5]);
        acc[r][6] = fmaf(xr[r], wb.z, acc[r][6]);
        acc[r][7] = fmaf(xr[r], wb.w, acc[r][7]);
      }
    }
  }
  float as_lo[4], as_hi[4], ad_lo[4], ad_hi[4];
  #pragma unroll
  for(int j=0;j<4;j++){
    as_lo[j] = Asv[tx*4+j];      ad_lo[j] = Adv[tx*4+j];
    as_hi[j] = Asv[64+tx*4+j];   ad_hi[j] = Adv[64+tx*4+j];
  }
  int q = tx >> 2;
  #pragma unroll
  for(int r=0;r<4;r++){
    int row = row0 + ty*4 + r;
    float ps_lo=0.f, ps_hi=0.f, pd_lo=0.f, pd_hi=0.f;
    #pragma unroll
    for(int j=0;j<4;j++){
      ps_lo = fmaf(acc[r][j],   as_lo[j], ps_lo);
      pd_lo = fmaf(acc[r][j],   ad_lo[j], pd_lo);
      ps_hi = fmaf(acc[r][4+j], as_hi[j], ps_hi);
      pd_hi = fmaf(acc[r][4+j], ad_hi[j], pd_hi);
    }
    ps_lo += __shfl_xor(ps_lo,1); ps_lo += __shfl_xor(ps_lo,2);
    pd_lo += __shfl_xor(pd_lo,1); pd_lo += __shfl_xor(pd_lo,2);
    ps_hi += __shfl_xor(ps_hi,1); ps_hi += __shfl_xor(ps_hi,2);
    pd_hi += __shfl_xor(pd_hi,1); pd_hi += __shfl_xor(pd_hi,2);
    if(row < N){
      u16* dst = h1b + (size_t)row*128;
      ushort4 a, b;
      a.x=f2bu(acc[r][0]); a.y=f2bu(acc[r][1]); a.z=f2bu(acc[r][2]); a.w=f2bu(acc[r][3]);
      b.x=f2bu(acc[r][4]); b.y=f2bu(acc[r][5]); b.z=f2bu(acc[r][6]); b.w=f2bu(acc[r][7]);
      *(ushort4*)(dst + tx*4)      = a;
      *(ushort4*)(dst + 64 + tx*4) = b;
      if((tx & 3) == 0){
        as1[row*8 + q]     = ps_lo;  as1[row*8 + 4 + q] = ps_hi;
        ad1[row*8 + q]     = pd_lo;  ad1[row*8 + 4 + q] = pd_hi;
      }
    }
  }
}

// ---------------- fused layer-1 aggregation (shared-exp, no max) ----------------
#define CH 32
__global__ __launch_bounds__(128) void k_agg1(const int* __restrict__ off,
                                              const int* __restrict__ csr,
                                              const float* __restrict__ as1,
                                              const float* __restrict__ ad1,
                                              const u16* __restrict__ h1b,
                                              const float* __restrict__ b1,
                                              u16* __restrict__ helu_b){
  __shared__ float wsm[CH*8];
  __shared__ int   ssm[CH];
  int node = blockIdx.x;
  int c = threadIdx.x;          // 0..127
  int h = c >> 4;               // head for phase B
  int beg = off[node], end = off[node+1];
  int el = c >> 3, hh = c & 7;  // phase-A: edge slot / head
  float advA = ad1[node*8 + hh];
  float den = 0.f, num = 0.f;
  for(int base = beg; base < end; base += CH){
    int cnt = end - base; if(cnt > CH) cnt = CH;
    __syncthreads();
    #pragma unroll
    for(int k=0; k<CH; k+=16){
      int e = el + k;
      if(e < cnt){
        int s = csr[base + e];
        if(hh == 0) ssm[e] = s;
        float v = as1[s*8 + hh] + advA;
        v = v > 0.f ? v : NEG*v;
        wsm[e*8 + hh] = __expf(v);          // softmax is shift-invariant; logits bounded
      }
    }
    __syncthreads();
    for(int e=0; e<cnt; e++){
      int s  = ssm[e];
      float w = wsm[e*8 + h];
      float xx = bu2f(h1b[(size_t)s*HH + c]);
      den += w;
      num = fmaf(w, xx, num);
    }
  }
  float res = num / (den + 1e-16f) + b1[c];
  helu_b[(size_t)node*HH + c] = f2bu(res > 0.f ? res : expm1f(res));
}

// ---------------- GEMM2 (bf16 in) + fused alpha2; h2 stored bf16 ----------------
__global__ __launch_bounds__(256) void k_gemm2(const u16* __restrict__ hb,
                                               const float* __restrict__ W2,
                                               const float* __restrict__ Asv,
                                               const float* __restrict__ Adv,
                                               u16* __restrict__ h2b,
                                               float* __restrict__ as2,
                                               float* __restrict__ ad2){
  __shared__ float Wl[128*16];
  int tid = threadIdx.x;
  const float4* W4 = (const float4*)W2;
  float4* Wl4 = (float4*)Wl;
  Wl4[tid]       = W4[tid];
  Wl4[tid + 256] = W4[tid + 256];
  __syncthreads();
  int i = blockIdx.x*16 + (tid >> 4);
  int c = tid & 15;
  if(i >= N) return;
  const uint4* h8 = (const uint4*)(hb + (size_t)i*HH);   // 16 chunks of 8 bf16
  float acc = 0.f;
  #pragma unroll
  for(int ch=0; ch<16; ch++){
    uint4 u = h8[ch];
    int k = ch*8;
    acc = fmaf(blo(u.x), Wl[(k+0)*16+c], acc);
    acc = fmaf(bhi(u.x), Wl[(k+1)*16+c], acc);
    acc = fmaf(blo(u.y), Wl[(k+2)*16+c], acc);
    acc = fmaf(bhi(u.y), Wl[(k+3)*16+c], acc);
    acc = fmaf(blo(u.z), Wl[(k+4)*16+c], acc);
    acc = fmaf(bhi(u.z), Wl[(k+5)*16+c], acc);
    acc = fmaf(blo(u.w), Wl[(k+6)*16+c], acc);
    acc = fmaf(bhi(u.w), Wl[(k+7)*16+c], acc);
  }
  h2b[(size_t)i*CLS + c] = f2bu(acc);
  float ps = acc * Asv[c];
  float pd = acc * Adv[c];
  ps += __shfl_xor(ps,1); ps += __shfl_xor(ps,2); ps += __shfl_xor(ps,4); ps += __shfl_xor(ps,8);
  pd += __shfl_xor(pd,1); pd += __shfl_xor(pd,2); pd += __shfl_xor(pd,4); pd += __shfl_xor(pd,8);
  if(c == 0){ as2[i] = ps; ad2[i] = pd; }
}

// ---------------- fused layer-2 aggregation (no max) + final bias ----------------
__global__ __launch_bounds__(256) void k_agg2(const int* __restrict__ off,
                                              const int* __restrict__ csr,
                                              const float* __restrict__ as2,
                                              const float* __restrict__ ad2,
                                              const u16* __restrict__ h2b,
                                              const float* __restrict__ b2,
                                              float* __restrict__ outp){
  int node = blockIdx.x*16 + (threadIdx.x >> 4);
  int c = threadIdx.x & 15;
  if(node >= N) return;
  int beg = off[node], end = off[node+1];
  float adv = ad2[node];
  float den = 0.f, num = 0.f;
  int e = beg;
  for(; e + 2 <= end; e += 2){
    int s0 = csr[e], s1 = csr[e+1];
    float v0 = as2[s0] + adv, v1 = as2[s1] + adv;
    v0 = v0 > 0.f ? v0 : NEG*v0;
    v1 = v1 > 0.f ? v1 : NEG*v1;
    float w0 = __expf(v0), w1 = __expf(v1);
    float x0 = bu2f(h2b[(size_t)s0*CLS + c]), x1 = bu2f(h2b[(size_t)s1*CLS + c]);
    den += w0 + w1;
    num = fmaf(w0, x0, num);
    num = fmaf(w1, x1, num);
  }
  for(; e < end; e++){
    int s = csr[e];
    float v = as2[s] + adv;
    v = v > 0.f ? v : NEG*v;
    float w = __expf(v);
    den += w;
    num = fmaf(w, bu2f(h2b[(size_t)s*CLS + c]), num);
  }
  outp[(size_t)node*CLS + c] = num / (den + 1e-16f) + b2[c];
}

extern "C" void kernel_launch(void* const* d_in, const int* in_sizes, int n_in,
                              void* d_out, int out_size, void* d_ws, size_t ws_size,
                              hipStream_t stream){
  const float* x     = (const float*)d_in[0];
  const int*   ei    = (const int*)  d_in[1];
  const float* W1    = (const float*)d_in[2];
  const float* av_s1 = (const float*)d_in[3];
  const float* av_d1 = (const float*)d_in[4];
  const float* b1    = (const float*)d_in[5];
  const float* W2    = (const float*)d_in[6];
  const float* av_s2 = (const float*)d_in[7];
  const float* av_d2 = (const float*)d_in[8];
  const float* b2    = (const float*)d_in[9];
  float* outp = (float*)d_out;

  char* p = (char*)d_ws;
  auto alloc = [&](size_t bytes){ char* q = p; p += (bytes + 255) & ~(size_t)255; return q; };
  u16*   h1b    = (u16*)  alloc((size_t)N*HH*2);
  u16*   helu_b = (u16*)  alloc((size_t)N*HH*2);
  u16*   h2b    = (u16*)  alloc((size_t)N*CLS*2);
  float* as1    = (float*)alloc((size_t)N*HEADS*4);
  float* ad1    = (float*)alloc((size_t)N*HEADS*4);
  float* as2    = (float*)alloc((size_t)N*4);
  float* ad2    = (float*)alloc((size_t)N*4);
  int*   deg    = (int*)  alloc((size_t)N*4);
  int*   off    = (int*)  alloc((size_t)(N+1)*4);
  int*   cursor = (int*)  alloc((size_t)N*4);
  int*   csr    = (int*)  alloc((size_t)ETOT*4);
  int*   bsum   = (int*)  alloc((size_t)NB*4);
  int*   boff   = (int*)  alloc((size_t)NB*4);

  // CSR build (shared by both layers)
  k_zero<<<(N+255)/256, 256, 0, stream>>>(deg);
  k_hist<<<(ETOT+255)/256, 256, 0, stream>>>(ei, deg);
  k_scan1<<<NB, 256, 0, stream>>>(deg, bsum);
  k_scan2<<<1, 256, 0, stream>>>(bsum, boff, off);
  k_scan3<<<NB, 256, 0, stream>>>(deg, boff, off, cursor);
  k_fill<<<(ETOT+255)/256, 256, 0, stream>>>(ei, cursor, csr);

  // layer 1
  k_gemm1<<<(N+BM-1)/BM, 256, 0, stream>>>(x, W1, av_s1, av_d1, h1b, as1, ad1);
  k_agg1<<<N, 128, 0, stream>>>(off, csr, as1, ad1, h1b, b1, helu_b);

  // layer 2
  k_gemm2<<<(N+15)/16, 256, 0, stream>>>(helu_b, W2, av_s2, av_d2, h2b, as2, ad2);
  k_agg2<<<(N+15)/16, 256, 0, stream>>>(off, csr, as2, ad2, h2b, b2, outp);
}

// Round 7
// 204.146 us; speedup vs baseline: 1.3144x; 1.0778x over previous
//
#include <hip/hip_runtime.h>
#include <hip/hip_bf16.h>
#include <limits.h>
#include <math.h>

#define N 50000
#define E_ 800000
#define ETOT 850000          // E + N self loops
#define HH 128               // HEADS*HID
#define HEADS 8
#define HID 16
#define CLS 16
#define NEG 0.2f
#define NB ((N + 255) / 256) // 196 scan blocks

typedef unsigned short u16;
typedef unsigned int   u32;

__device__ __forceinline__ u16 f2bu(float f){           // f32 -> bf16 RNE
  union{float f; u32 i;} c; c.f = f;
  u32 lsb = (c.i >> 16) & 1u;
  c.i += 0x7fffu + lsb;
  return (u16)(c.i >> 16);
}
__device__ __forceinline__ float bu2f(u16 u){           // bf16 -> f32
  union{u32 i; float f;} c; c.i = ((u32)u) << 16; return c.f;
}
__device__ __forceinline__ float blo(u32 u){ union{u32 i; float f;} c; c.i = u << 16; return c.f; }
__device__ __forceinline__ float bhi(u32 u){ union{u32 i; float f;} c; c.i = u & 0xffff0000u; return c.f; }

// ---------------- CSR build ----------------
__global__ __launch_bounds__(256) void k_hist(const int* __restrict__ ei, int* __restrict__ deg){
  int e = blockIdx.x*256 + threadIdx.x;
  if(e >= ETOT) return;
  int d = (e < E_) ? ei[E_ + e] : e - E_;
  atomicAdd(&deg[d], 1);
}

__global__ __launch_bounds__(256) void k_scan1(const int* __restrict__ deg, int* __restrict__ bsum){
  __shared__ int sm[256];
  int t = threadIdx.x;
  int i = blockIdx.x*256 + t;
  sm[t] = (i < N) ? deg[i] : 0;
  __syncthreads();
  #pragma unroll
  for(int ofs=128; ofs>0; ofs>>=1){
    if(t < ofs) sm[t] += sm[t+ofs];
    __syncthreads();
  }
  if(t == 0) bsum[blockIdx.x] = sm[0];
}

__global__ __launch_bounds__(256) void k_scan2(const int* __restrict__ bsum,
                                               int* __restrict__ boff,
                                               int* __restrict__ off){
  __shared__ int sm[256];
  int t = threadIdx.x;
  sm[t] = (t < NB) ? bsum[t] : 0;
  __syncthreads();
  #pragma unroll
  for(int ofs=1; ofs<256; ofs<<=1){
    int v = sm[t];
    int add = (t >= ofs) ? sm[t-ofs] : 0;
    __syncthreads();
    sm[t] = v + add;
    __syncthreads();
  }
  if(t < NB) boff[t] = (t == 0) ? 0 : sm[t-1];
  if(t == 255) off[N] = sm[NB-1];
}

__global__ __launch_bounds__(256) void k_scan3(const int* __restrict__ deg,
                                               const int* __restrict__ boff,
                                               int* __restrict__ off,
                                               int* __restrict__ cursor){
  __shared__ int sm[256];
  int t = threadIdx.x;
  int i = blockIdx.x*256 + t;
  int v0 = (i < N) ? deg[i] : 0;
  sm[t] = v0;
  __syncthreads();
  #pragma unroll
  for(int ofs=1; ofs<256; ofs<<=1){
    int v = sm[t];
    int add = (t >= ofs) ? sm[t-ofs] : 0;
    __syncthreads();
    sm[t] = v + add;
    __syncthreads();
  }
  if(i < N){
    int excl = boff[blockIdx.x] + sm[t] - v0;
    off[i] = excl;
    cursor[i] = excl;
  }
}

__global__ __launch_bounds__(256) void k_fill(const int* __restrict__ ei,
                                              int* __restrict__ cursor,
                                              int* __restrict__ csr_src){
  int e = blockIdx.x*256 + threadIdx.x;
  if(e >= ETOT) return;
  int s, d;
  if(e < E_){ s = ei[e]; d = ei[E_ + e]; } else { s = d = e - E_; }
  int pos = atomicAdd(&cursor[d], 1);
  csr_src[pos] = s;
}

// ---------------- GEMM1 + fused alpha1 epilogue; h1 stored bf16 ----------------
#define BM 64
#define BKK 32
__global__ __launch_bounds__(256) void k_gemm1(const float* __restrict__ x,
                                               const float* __restrict__ W,
                                               const float* __restrict__ Asv,
                                               const float* __restrict__ Adv,
                                               u16* __restrict__ h1b,
                                               float* __restrict__ as1,
                                               float* __restrict__ ad1){
  __shared__ float xT[BKK*BM];      // 8 KiB
  __shared__ float Wl[BKK*128];     // 16 KiB, xor-swizzled
  int tid = threadIdx.x;
  int row0 = blockIdx.x * BM;
  int tx = tid & 15;
  int ty = tid >> 4;
  float acc[4][8];
  #pragma unroll
  for(int r=0;r<4;r++)
    #pragma unroll
    for(int j=0;j<8;j++) acc[r][j]=0.f;

  int lr = tid >> 2;
  int lk = (tid & 3) * 8;
  int wr = tid >> 3;
  int wc = (tid & 7) * 16;
  int xrow = row0 + lr; if(xrow >= N) xrow = N-1;
  const float* xbase = x + (size_t)xrow*128;

  for(int k0=0; k0<128; k0+=BKK){
    float4 v0 = *(const float4*)(xbase + k0 + lk);
    float4 v1 = *(const float4*)(xbase + k0 + lk + 4);
    float4 wv0, wv1, wv2, wv3;
    {
      const float4* wsrc = (const float4*)(W + (size_t)(k0+wr)*128 + wc);
      wv0 = wsrc[0]; wv1 = wsrc[1]; wv2 = wsrc[2]; wv3 = wsrc[3];
    }
    __syncthreads();
    xT[(lk+0)*BM + lr] = v0.x;
    xT[(lk+1)*BM + lr] = v0.y;
    xT[(lk+2)*BM + lr] = v0.z;
    xT[(lk+3)*BM + lr] = v0.w;
    xT[(lk+4)*BM + lr] = v1.x;
    xT[(lk+5)*BM + lr] = v1.y;
    xT[(lk+6)*BM + lr] = v1.z;
    xT[(lk+7)*BM + lr] = v1.w;
    {
      char* wl = (char*)Wl;
      int swz = (wr & 7) << 4;
      int b = (wr*128 + wc)*4;
      *(float4*)(wl + ((b      ) ^ swz)) = wv0;
      *(float4*)(wl + ((b + 16 ) ^ swz)) = wv1;
      *(float4*)(wl + ((b + 32 ) ^ swz)) = wv2;
      *(float4*)(wl + ((b + 48 ) ^ swz)) = wv3;
    }
    __syncthreads();
    #pragma unroll 8
    for(int k=0;k<BKK;k++){
      float4 xv = *(const float4*)&xT[k*BM + ty*4];
      const char* wl = (const char*)Wl;
      int swz = (k & 7) << 4;
      float4 wa = *(const float4*)(wl + ((k*512 + tx*16      ) ^ swz));
      float4 wb = *(const float4*)(wl + ((k*512 + 256 + tx*16) ^ swz));
      float xr[4] = {xv.x, xv.y, xv.z, xv.w};
      #pragma unroll
      for(int r=0;r<4;r++){
        acc[r][0] = fmaf(xr[r], wa.x, acc[r][0]);
        acc[r][1] = fmaf(xr[r], wa.y, acc[r][1]);
        acc[r][2] = fmaf(xr[r], wa.z, acc[r][2]);
        acc[r][3] = fmaf(xr[r], wa.w, acc[r][3]);
        acc[r][4] = fmaf(xr[r], wb.x, acc[r][4]);
        acc[r][5] = fmaf(xr[r], wb.y, acc[r][5]);
        acc[r][6] = fmaf(xr[r], wb.z, acc[r][6]);
        acc[r][7] = fmaf(xr[r], wb.w, acc[r][7]);
      }
    }
  }
  float as_lo[4], as_hi[4], ad_lo[4], ad_hi[4];
  #pragma unroll
  for(int j=0;j<4;j++){
    as_lo[j] = Asv[tx*4+j];      ad_lo[j] = Adv[tx*4+j];
    as_hi[j] = Asv[64+tx*4+j];   ad_hi[j] = Adv[64+tx*4+j];
  }
  int q = tx >> 2;
  #pragma unroll
  for(int r=0;r<4;r++){
    int row = row0 + ty*4 + r;
    float ps_lo=0.f, ps_hi=0.f, pd_lo=0.f, pd_hi=0.f;
    #pragma unroll
    for(int j=0;j<4;j++){
      ps_lo = fmaf(acc[r][j],   as_lo[j], ps_lo);
      pd_lo = fmaf(acc[r][j],   ad_lo[j], pd_lo);
      ps_hi = fmaf(acc[r][4+j], as_hi[j], ps_hi);
      pd_hi = fmaf(acc[r][4+j], ad_hi[j], pd_hi);
    }
    ps_lo += __shfl_xor(ps_lo,1); ps_lo += __shfl_xor(ps_lo,2);
    pd_lo += __shfl_xor(pd_lo,1); pd_lo += __shfl_xor(pd_lo,2);
    ps_hi += __shfl_xor(ps_hi,1); ps_hi += __shfl_xor(ps_hi,2);
    pd_hi += __shfl_xor(pd_hi,1); pd_hi += __shfl_xor(pd_hi,2);
    if(row < N){
      u16* dst = h1b + (size_t)row*128;
      ushort4 a, b;
      a.x=f2bu(acc[r][0]); a.y=f2bu(acc[r][1]); a.z=f2bu(acc[r][2]); a.w=f2bu(acc[r][3]);
      b.x=f2bu(acc[r][4]); b.y=f2bu(acc[r][5]); b.z=f2bu(acc[r][6]); b.w=f2bu(acc[r][7]);
      *(ushort4*)(dst + tx*4)      = a;
      *(ushort4*)(dst + 64 + tx*4) = b;
      if((tx & 3) == 0){
        as1[row*8 + q]     = ps_lo;  as1[row*8 + 4 + q] = ps_hi;
        ad1[row*8 + q]     = pd_lo;  ad1[row*8 + 4 + q] = pd_hi;
      }
    }
  }
}

// ---------------- fused layer-1 aggregation: 1 wave/node, u32 loads ----------------
#define CH 32
__global__ __launch_bounds__(256) void k_agg1(const int* __restrict__ off,
                                              const int* __restrict__ csr,
                                              const float* __restrict__ as1,
                                              const float* __restrict__ ad1,
                                              const u32* __restrict__ h1w,
                                              const float* __restrict__ b1,
                                              u32* __restrict__ helu_w){
  __shared__ float wsm[4][CH*8];
  __shared__ int   ssm[4][CH];
  int wv   = threadIdx.x >> 6;
  int lane = threadIdx.x & 63;
  int node = blockIdx.x*4 + wv;          // grid = N/4 exactly
  int beg = off[node], end = off[node+1];
  int h  = lane >> 3;                    // head (channels 2*lane, 2*lane+1)
  int hh = lane & 7;                     // phase-A head
  int el = lane >> 3;                    // phase-A edge slot
  float advA = ad1[node*8 + hh];
  float den = 0.f, num0 = 0.f, num1 = 0.f;
  float* wsw = wsm[wv];
  int*   ssw = ssm[wv];
  for(int base = beg; base < end; base += CH){
    int cnt = end - base; if(cnt > CH) cnt = CH;
    // phase A: wave-private; lane (el,hh) covers edges el, el+8, el+16, el+24
    #pragma unroll
    for(int k=0;k<CH;k+=8){
      int e = el + k;
      if(e < cnt){
        int s = csr[base+e];
        if(hh == 0) ssw[e] = s;
        float v = as1[s*8+hh] + advA;
        v = v > 0.f ? v : NEG*v;
        wsw[e*8+hh] = __expf(v);         // shift-invariant softmax; logits bounded
      }
    }
    // phase B: wave-synchronous (no barrier needed), 4 gathers in flight
    int e = 0;
    for(; e+4 <= cnt; e += 4){
      int s0 = ssw[e], s1 = ssw[e+1], s2 = ssw[e+2], s3 = ssw[e+3];
      float w0 = wsw[e*8+h], w1 = wsw[e*8+8+h], w2 = wsw[e*8+16+h], w3 = wsw[e*8+24+h];
      u32 u0 = h1w[(size_t)s0*64 + lane];
      u32 u1 = h1w[(size_t)s1*64 + lane];
      u32 u2 = h1w[(size_t)s2*64 + lane];
      u32 u3 = h1w[(size_t)s3*64 + lane];
      den += (w0+w1)+(w2+w3);
      num0 = fmaf(w0, blo(u0), num0); num1 = fmaf(w0, bhi(u0), num1);
      num0 = fmaf(w1, blo(u1), num0); num1 = fmaf(w1, bhi(u1), num1);
      num0 = fmaf(w2, blo(u2), num0); num1 = fmaf(w2, bhi(u2), num1);
      num0 = fmaf(w3, blo(u3), num0); num1 = fmaf(w3, bhi(u3), num1);
    }
    for(; e < cnt; e++){
      int s = ssw[e];
      float w = wsw[e*8+h];
      u32 u = h1w[(size_t)s*64 + lane];
      den += w;
      num0 = fmaf(w, blo(u), num0);
      num1 = fmaf(w, bhi(u), num1);
    }
  }
  float2 bb = ((const float2*)b1)[lane];
  float inv = 1.f / (den + 1e-16f);
  float r0 = num0*inv + bb.x;
  float r1 = num1*inv + bb.y;
  r0 = r0 > 0.f ? r0 : expm1f(r0);
  r1 = r1 > 0.f ? r1 : expm1f(r1);
  helu_w[(size_t)node*64 + lane] = (u32)f2bu(r0) | ((u32)f2bu(r1) << 16);
}

// ---------------- GEMM2 (bf16 in) + fused alpha2; h2 stored bf16 ----------------
__global__ __launch_bounds__(256) void k_gemm2(const u16* __restrict__ hb,
                                               const float* __restrict__ W2,
                                               const float* __restrict__ Asv,
                                               const float* __restrict__ Adv,
                                               u16* __restrict__ h2b,
                                               float* __restrict__ as2,
                                               float* __restrict__ ad2){
  __shared__ float Wl[128*16];
  int tid = threadIdx.x;
  const float4* W4 = (const float4*)W2;
  float4* Wl4 = (float4*)Wl;
  Wl4[tid]       = W4[tid];
  Wl4[tid + 256] = W4[tid + 256];
  __syncthreads();
  int i = blockIdx.x*16 + (tid >> 4);
  int c = tid & 15;
  if(i >= N) return;
  const uint4* h8 = (const uint4*)(hb + (size_t)i*HH);
  float acc = 0.f;
  #pragma unroll
  for(int ch=0; ch<16; ch++){
    uint4 u = h8[ch];
    int k = ch*8;
    acc = fmaf(blo(u.x), Wl[(k+0)*16+c], acc);
    acc = fmaf(bhi(u.x), Wl[(k+1)*16+c], acc);
    acc = fmaf(blo(u.y), Wl[(k+2)*16+c], acc);
    acc = fmaf(bhi(u.y), Wl[(k+3)*16+c], acc);
    acc = fmaf(blo(u.z), Wl[(k+4)*16+c], acc);
    acc = fmaf(bhi(u.z), Wl[(k+5)*16+c], acc);
    acc = fmaf(blo(u.w), Wl[(k+6)*16+c], acc);
    acc = fmaf(bhi(u.w), Wl[(k+7)*16+c], acc);
  }
  h2b[(size_t)i*CLS + c] = f2bu(acc);
  float ps = acc * Asv[c];
  float pd = acc * Adv[c];
  ps += __shfl_xor(ps,1); ps += __shfl_xor(ps,2); ps += __shfl_xor(ps,4); ps += __shfl_xor(ps,8);
  pd += __shfl_xor(pd,1); pd += __shfl_xor(pd,2); pd += __shfl_xor(pd,4); pd += __shfl_xor(pd,8);
  if(c == 0){ as2[i] = ps; ad2[i] = pd; }
}

// ---------------- fused layer-2 aggregation: 8 lanes/node, shfl-shared exp ----------------
__global__ __launch_bounds__(256) void k_agg2(const int* __restrict__ off,
                                              const int* __restrict__ csr,
                                              const float* __restrict__ as2,
                                              const float* __restrict__ ad2,
                                              const u32* __restrict__ h2w,
                                              const float* __restrict__ b2,
                                              float* __restrict__ outp){
  int t = threadIdx.x;
  int node = blockIdx.x*32 + (t >> 3);
  int c2 = t & 7;                        // channels 2*c2, 2*c2+1
  if(node >= N) return;
  int beg = off[node], end = off[node+1];
  float adv = ad2[node];
  float den = 0.f, num0 = 0.f, num1 = 0.f;
  for(int base = beg; base < end; base += 8){
    int cnt = end - base; if(cnt > 8) cnt = 8;
    float w_my = 0.f; int s_my = 0;
    if(c2 < cnt){
      s_my = csr[base + c2];
      float v = as2[s_my] + adv;
      v = v > 0.f ? v : NEG*v;
      w_my = __expf(v);
    }
    #pragma unroll
    for(int j=0; j<8; j++){
      if(j >= cnt) break;
      int src = (t & 56) | j;            // lane within wave: (wl & ~7) | j
      float w = __shfl(w_my, src);
      int   s = __shfl(s_my, src);
      u32 u = h2w[(size_t)s*8 + c2];
      den += w;
      num0 = fmaf(w, blo(u), num0);
      num1 = fmaf(w, bhi(u), num1);
    }
  }
  float inv = 1.f / (den + 1e-16f);
  float2 bb = ((const float2*)b2)[c2];
  float2 r;
  r.x = num0*inv + bb.x;
  r.y = num1*inv + bb.y;
  ((float2*)outp)[(size_t)node*8 + c2] = r;
}

extern "C" void kernel_launch(void* const* d_in, const int* in_sizes, int n_in,
                              void* d_out, int out_size, void* d_ws, size_t ws_size,
                              hipStream_t stream){
  const float* x     = (const float*)d_in[0];
  const int*   ei    = (const int*)  d_in[1];
  const float* W1    = (const float*)d_in[2];
  const float* av_s1 = (const float*)d_in[3];
  const float* av_d1 = (const float*)d_in[4];
  const float* b1    = (const float*)d_in[5];
  const float* W2    = (const float*)d_in[6];
  const float* av_s2 = (const float*)d_in[7];
  const float* av_d2 = (const float*)d_in[8];
  const float* b2    = (const float*)d_in[9];
  float* outp = (float*)d_out;

  char* p = (char*)d_ws;
  auto alloc = [&](size_t bytes){ char* q = p; p += (bytes + 255) & ~(size_t)255; return q; };
  u16*   h1b    = (u16*)  alloc((size_t)N*HH*2);
  u16*   helu_b = (u16*)  alloc((size_t)N*HH*2);
  u16*   h2b    = (u16*)  alloc((size_t)N*CLS*2);
  float* as1    = (float*)alloc((size_t)N*HEADS*4);
  float* ad1    = (float*)alloc((size_t)N*HEADS*4);
  float* as2    = (float*)alloc((size_t)N*4);
  float* ad2    = (float*)alloc((size_t)N*4);
  int*   deg    = (int*)  alloc((size_t)N*4);
  int*   off    = (int*)  alloc((size_t)(N+1)*4);
  int*   cursor = (int*)  alloc((size_t)N*4);
  int*   csr    = (int*)  alloc((size_t)ETOT*4);
  int*   bsum   = (int*)  alloc((size_t)NB*4);
  int*   boff   = (int*)  alloc((size_t)NB*4);

  // CSR build (shared by both layers)
  hipMemsetAsync(deg, 0, (size_t)N*4, stream);
  k_hist<<<(ETOT+255)/256, 256, 0, stream>>>(ei, deg);
  k_scan1<<<NB, 256, 0, stream>>>(deg, bsum);
  k_scan2<<<1, 256, 0, stream>>>(bsum, boff, off);
  k_scan3<<<NB, 256, 0, stream>>>(deg, boff, off, cursor);
  k_fill<<<(ETOT+255)/256, 256, 0, stream>>>(ei, cursor, csr);

  // layer 1
  k_gemm1<<<(N+BM-1)/BM, 256, 0, stream>>>(x, W1, av_s1, av_d1, h1b, as1, ad1);
  k_agg1<<<N/4, 256, 0, stream>>>(off, csr, as1, ad1, (const u32*)h1b, b1, (u32*)helu_b);

  // layer 2
  k_gemm2<<<(N+15)/16, 256, 0, stream>>>(helu_b, W2, av_s2, av_d2, h2b, as2, ad2);
  k_agg2<<<(N+31)/32, 256, 0, stream>>>(off, csr, as2, ad2, (const u32*)h2b, b2, outp);
}

// Round 8
// 172.447 us; speedup vs baseline: 1.5560x; 1.1838x over previous
//
#include <hip/hip_runtime.h>
#include <hip/hip_bf16.h>
#include <limits.h>
#include <math.h>

#define N 50000
#define E_ 800000
#define ETOT 850000          // E + N self loops
#define HH 128               // HEADS*HID
#define HEADS 8
#define HID 16
#define CLS 16
#define NEG 0.2f
#define NB ((N + 255) / 256) // 196 scan blocks
#define GEMM_NB ((N + 63) / 64)          // 782 gemm blocks
#define LINK_NB ((ETOT + 255) / 256)     // 3321 link blocks

typedef unsigned short u16;
typedef unsigned int   u32;
typedef unsigned long long u64;

__device__ __forceinline__ u16 f2bu(float f){           // f32 -> bf16 RNE
  union{float f; u32 i;} c; c.f = f;
  u32 lsb = (c.i >> 16) & 1u;
  c.i += 0x7fffu + lsb;
  return (u16)(c.i >> 16);
}
__device__ __forceinline__ float blo(u32 u){ union{u32 i; float f;} c; c.i = u << 16; return c.f; }
__device__ __forceinline__ float bhi(u32 u){ union{u32 i; float f;} c; c.i = u & 0xffff0000u; return c.f; }

// ---------------- fused GEMM1 (+alpha1 epilogue) and hist+link edge pass ----------------
#define BM 64
#define BKK 32
__global__ __launch_bounds__(256) void k_gemm1link(const float* __restrict__ x,
                                                   const float* __restrict__ W,
                                                   const float* __restrict__ Asv,
                                                   const float* __restrict__ Adv,
                                                   u16* __restrict__ h1b,
                                                   float* __restrict__ as1,
                                                   float* __restrict__ ad1,
                                                   const int* __restrict__ ei,
                                                   int* __restrict__ deg,
                                                   int* __restrict__ head,
                                                   u64* __restrict__ next_src){
  __shared__ float xT[BKK*BM];      // 8 KiB
  __shared__ float Wl[BKK*128];     // 16 KiB, xor-swizzled
  if(blockIdx.x >= GEMM_NB){
    // ---- hist + linked-list build (coalesced next_src writes) ----
    int e = (blockIdx.x - GEMM_NB)*256 + threadIdx.x;
    if(e < ETOT){
      int s, d;
      if(e < E_){ s = ei[e]; d = ei[E_ + e]; } else { s = d = e - E_; }
      atomicAdd(&deg[d], 1);
      int old = atomicExch(&head[d], e);
      next_src[e] = ((u64)(u32)s << 32) | (u32)old;
    }
    return;
  }
  // ---- GEMM1 ----
  int tid = threadIdx.x;
  int row0 = blockIdx.x * BM;
  int tx = tid & 15;
  int ty = tid >> 4;
  float acc[4][8];
  #pragma unroll
  for(int r=0;r<4;r++)
    #pragma unroll
    for(int j=0;j<8;j++) acc[r][j]=0.f;

  int lr = tid >> 2;
  int lk = (tid & 3) * 8;
  int wr = tid >> 3;
  int wc = (tid & 7) * 16;
  int xrow = row0 + lr; if(xrow >= N) xrow = N-1;
  const float* xbase = x + (size_t)xrow*128;

  for(int k0=0; k0<128; k0+=BKK){
    float4 v0 = *(const float4*)(xbase + k0 + lk);
    float4 v1 = *(const float4*)(xbase + k0 + lk + 4);
    float4 wv0, wv1, wv2, wv3;
    {
      const float4* wsrc = (const float4*)(W + (size_t)(k0+wr)*128 + wc);
      wv0 = wsrc[0]; wv1 = wsrc[1]; wv2 = wsrc[2]; wv3 = wsrc[3];
    }
    __syncthreads();
    xT[(lk+0)*BM + lr] = v0.x;
    xT[(lk+1)*BM + lr] = v0.y;
    xT[(lk+2)*BM + lr] = v0.z;
    xT[(lk+3)*BM + lr] = v0.w;
    xT[(lk+4)*BM + lr] = v1.x;
    xT[(lk+5)*BM + lr] = v1.y;
    xT[(lk+6)*BM + lr] = v1.z;
    xT[(lk+7)*BM + lr] = v1.w;
    {
      char* wl = (char*)Wl;
      int swz = (wr & 7) << 4;
      int b = (wr*128 + wc)*4;
      *(float4*)(wl + ((b      ) ^ swz)) = wv0;
      *(float4*)(wl + ((b + 16 ) ^ swz)) = wv1;
      *(float4*)(wl + ((b + 32 ) ^ swz)) = wv2;
      *(float4*)(wl + ((b + 48 ) ^ swz)) = wv3;
    }
    __syncthreads();
    #pragma unroll 8
    for(int k=0;k<BKK;k++){
      float4 xv = *(const float4*)&xT[k*BM + ty*4];
      const char* wl = (const char*)Wl;
      int swz = (k & 7) << 4;
      float4 wa = *(const float4*)(wl + ((k*512 + tx*16      ) ^ swz));
      float4 wb = *(const float4*)(wl + ((k*512 + 256 + tx*16) ^ swz));
      float xr[4] = {xv.x, xv.y, xv.z, xv.w};
      #pragma unroll
      for(int r=0;r<4;r++){
        acc[r][0] = fmaf(xr[r], wa.x, acc[r][0]);
        acc[r][1] = fmaf(xr[r], wa.y, acc[r][1]);
        acc[r][2] = fmaf(xr[r], wa.z, acc[r][2]);
        acc[r][3] = fmaf(xr[r], wa.w, acc[r][3]);
        acc[r][4] = fmaf(xr[r], wb.x, acc[r][4]);
        acc[r][5] = fmaf(xr[r], wb.y, acc[r][5]);
        acc[r][6] = fmaf(xr[r], wb.z, acc[r][6]);
        acc[r][7] = fmaf(xr[r], wb.w, acc[r][7]);
      }
    }
  }
  float as_lo[4], as_hi[4], ad_lo[4], ad_hi[4];
  #pragma unroll
  for(int j=0;j<4;j++){
    as_lo[j] = Asv[tx*4+j];      ad_lo[j] = Adv[tx*4+j];
    as_hi[j] = Asv[64+tx*4+j];   ad_hi[j] = Adv[64+tx*4+j];
  }
  int q = tx >> 2;
  #pragma unroll
  for(int r=0;r<4;r++){
    int row = row0 + ty*4 + r;
    float ps_lo=0.f, ps_hi=0.f, pd_lo=0.f, pd_hi=0.f;
    #pragma unroll
    for(int j=0;j<4;j++){
      ps_lo = fmaf(acc[r][j],   as_lo[j], ps_lo);
      pd_lo = fmaf(acc[r][j],   ad_lo[j], pd_lo);
      ps_hi = fmaf(acc[r][4+j], as_hi[j], ps_hi);
      pd_hi = fmaf(acc[r][4+j], ad_hi[j], pd_hi);
    }
    ps_lo += __shfl_xor(ps_lo,1); ps_lo += __shfl_xor(ps_lo,2);
    pd_lo += __shfl_xor(pd_lo,1); pd_lo += __shfl_xor(pd_lo,2);
    ps_hi += __shfl_xor(ps_hi,1); ps_hi += __shfl_xor(ps_hi,2);
    pd_hi += __shfl_xor(pd_hi,1); pd_hi += __shfl_xor(pd_hi,2);
    if(row < N){
      u16* dst = h1b + (size_t)row*128;
      ushort4 a, b;
      a.x=f2bu(acc[r][0]); a.y=f2bu(acc[r][1]); a.z=f2bu(acc[r][2]); a.w=f2bu(acc[r][3]);
      b.x=f2bu(acc[r][4]); b.y=f2bu(acc[r][5]); b.z=f2bu(acc[r][6]); b.w=f2bu(acc[r][7]);
      *(ushort4*)(dst + tx*4)      = a;
      *(ushort4*)(dst + 64 + tx*4) = b;
      if((tx & 3) == 0){
        as1[row*8 + q]     = ps_lo;  as1[row*8 + 4 + q] = ps_hi;
        ad1[row*8 + q]     = pd_lo;  ad1[row*8 + 4 + q] = pd_hi;
      }
    }
  }
}

// ---------------- scan stages ----------------
__global__ __launch_bounds__(256) void k_scan1(const int* __restrict__ deg, int* __restrict__ bsum){
  __shared__ int sm[256];
  int t = threadIdx.x;
  int i = blockIdx.x*256 + t;
  sm[t] = (i < N) ? deg[i] : 0;
  __syncthreads();
  #pragma unroll
  for(int ofs=128; ofs>0; ofs>>=1){
    if(t < ofs) sm[t] += sm[t+ofs];
    __syncthreads();
  }
  if(t == 0) bsum[blockIdx.x] = sm[0];
}

__global__ __launch_bounds__(256) void k_scan2(const int* __restrict__ bsum,
                                               int* __restrict__ boff,
                                               int* __restrict__ off){
  __shared__ int sm[256];
  int t = threadIdx.x;
  sm[t] = (t < NB) ? bsum[t] : 0;
  __syncthreads();
  #pragma unroll
  for(int ofs=1; ofs<256; ofs<<=1){
    int v = sm[t];
    int add = (t >= ofs) ? sm[t-ofs] : 0;
    __syncthreads();
    sm[t] = v + add;
    __syncthreads();
  }
  if(t < NB) boff[t] = (t == 0) ? 0 : sm[t-1];
  if(t == 255) off[N] = sm[NB-1];
}

// stage 3 + linked-list walk: off[] + sequential per-node CSR fill
__global__ __launch_bounds__(256) void k_scan3walk(const int* __restrict__ deg,
                                                   const int* __restrict__ boff,
                                                   const int* __restrict__ head,
                                                   const u64* __restrict__ next_src,
                                                   int* __restrict__ off,
                                                   int* __restrict__ csr){
  __shared__ int sm[256];
  int t = threadIdx.x;
  int i = blockIdx.x*256 + t;
  int v0 = (i < N) ? deg[i] : 0;
  sm[t] = v0;
  __syncthreads();
  #pragma unroll
  for(int ofs=1; ofs<256; ofs<<=1){
    int v = sm[t];
    int add = (t >= ofs) ? sm[t-ofs] : 0;
    __syncthreads();
    sm[t] = v + add;
    __syncthreads();
  }
  if(i < N){
    int excl = boff[blockIdx.x] + sm[t] - v0;
    off[i] = excl;
    int e = head[i];
    int pos = excl;
    while(e >= 0){
      u64 v = next_src[e];
      csr[pos++] = (int)(v >> 32);
      e = (int)(u32)(v & 0xffffffffu);
    }
  }
}

// ---------------- fused layer-1 aggregation: 1 wave/node, u32 loads ----------------
#define CH 32
__global__ __launch_bounds__(256) void k_agg1(const int* __restrict__ off,
                                              const int* __restrict__ csr,
                                              const float* __restrict__ as1,
                                              const float* __restrict__ ad1,
                                              const u32* __restrict__ h1w,
                                              const float* __restrict__ b1,
                                              u32* __restrict__ helu_w){
  __shared__ float wsm[4][CH*8];
  __shared__ int   ssm[4][CH];
  int wv   = threadIdx.x >> 6;
  int lane = threadIdx.x & 63;
  int node = blockIdx.x*4 + wv;          // grid = N/4 exactly
  int beg = off[node], end = off[node+1];
  int h  = lane >> 3;                    // head (channels 2*lane, 2*lane+1)
  int hh = lane & 7;                     // phase-A head
  int el = lane >> 3;                    // phase-A edge slot
  float advA = ad1[node*8 + hh];
  float den = 0.f, num0 = 0.f, num1 = 0.f;
  float* wsw = wsm[wv];
  int*   ssw = ssm[wv];
  for(int base = beg; base < end; base += CH){
    int cnt = end - base; if(cnt > CH) cnt = CH;
    #pragma unroll
    for(int k=0;k<CH;k+=8){
      int e = el + k;
      if(e < cnt){
        int s = csr[base+e];
        if(hh == 0) ssw[e] = s;
        float v = as1[s*8+hh] + advA;
        v = v > 0.f ? v : NEG*v;
        wsw[e*8+hh] = __expf(v);         // shift-invariant softmax; logits bounded
      }
    }
    int e = 0;
    for(; e+4 <= cnt; e += 4){
      int s0 = ssw[e], s1 = ssw[e+1], s2 = ssw[e+2], s3 = ssw[e+3];
      float w0 = wsw[e*8+h], w1 = wsw[e*8+8+h], w2 = wsw[e*8+16+h], w3 = wsw[e*8+24+h];
      u32 u0 = h1w[(size_t)s0*64 + lane];
      u32 u1 = h1w[(size_t)s1*64 + lane];
      u32 u2 = h1w[(size_t)s2*64 + lane];
      u32 u3 = h1w[(size_t)s3*64 + lane];
      den += (w0+w1)+(w2+w3);
      num0 = fmaf(w0, blo(u0), num0); num1 = fmaf(w0, bhi(u0), num1);
      num0 = fmaf(w1, blo(u1), num0); num1 = fmaf(w1, bhi(u1), num1);
      num0 = fmaf(w2, blo(u2), num0); num1 = fmaf(w2, bhi(u2), num1);
      num0 = fmaf(w3, blo(u3), num0); num1 = fmaf(w3, bhi(u3), num1);
    }
    for(; e < cnt; e++){
      int s = ssw[e];
      float w = wsw[e*8+h];
      u32 u = h1w[(size_t)s*64 + lane];
      den += w;
      num0 = fmaf(w, blo(u), num0);
      num1 = fmaf(w, bhi(u), num1);
    }
  }
  float2 bb = ((const float2*)b1)[lane];
  float inv = 1.f / (den + 1e-16f);
  float r0 = num0*inv + bb.x;
  float r1 = num1*inv + bb.y;
  r0 = r0 > 0.f ? r0 : expm1f(r0);
  r1 = r1 > 0.f ? r1 : expm1f(r1);
  helu_w[(size_t)node*64 + lane] = (u32)f2bu(r0) | ((u32)f2bu(r1) << 16);
}

// ---------------- GEMM2 (bf16 in) + fused alpha2; h2 stored bf16 ----------------
__global__ __launch_bounds__(256) void k_gemm2(const u16* __restrict__ hb,
                                               const float* __restrict__ W2,
                                               const float* __restrict__ Asv,
                                               const float* __restrict__ Adv,
                                               u16* __restrict__ h2b,
                                               float* __restrict__ as2,
                                               float* __restrict__ ad2){
  __shared__ float Wl[128*16];
  int tid = threadIdx.x;
  const float4* W4 = (const float4*)W2;
  float4* Wl4 = (float4*)Wl;
  Wl4[tid]       = W4[tid];
  Wl4[tid + 256] = W4[tid + 256];
  __syncthreads();
  int i = blockIdx.x*16 + (tid >> 4);
  int c = tid & 15;
  if(i >= N) return;
  const uint4* h8 = (const uint4*)(hb + (size_t)i*HH);
  float acc = 0.f;
  #pragma unroll
  for(int ch=0; ch<16; ch++){
    uint4 u = h8[ch];
    int k = ch*8;
    acc = fmaf(blo(u.x), Wl[(k+0)*16+c], acc);
    acc = fmaf(bhi(u.x), Wl[(k+1)*16+c], acc);
    acc = fmaf(blo(u.y), Wl[(k+2)*16+c], acc);
    acc = fmaf(bhi(u.y), Wl[(k+3)*16+c], acc);
    acc = fmaf(blo(u.z), Wl[(k+4)*16+c], acc);
    acc = fmaf(bhi(u.z), Wl[(k+5)*16+c], acc);
    acc = fmaf(blo(u.w), Wl[(k+6)*16+c], acc);
    acc = fmaf(bhi(u.w), Wl[(k+7)*16+c], acc);
  }
  h2b[(size_t)i*CLS + c] = f2bu(acc);
  float ps = acc * Asv[c];
  float pd = acc * Adv[c];
  ps += __shfl_xor(ps,1); ps += __shfl_xor(ps,2); ps += __shfl_xor(ps,4); ps += __shfl_xor(ps,8);
  pd += __shfl_xor(pd,1); pd += __shfl_xor(pd,2); pd += __shfl_xor(pd,4); pd += __shfl_xor(pd,8);
  if(c == 0){ as2[i] = ps; ad2[i] = pd; }
}

// ---------------- fused layer-2 aggregation: 8 lanes/node, shfl-shared exp ----------------
__global__ __launch_bounds__(256) void k_agg2(const int* __restrict__ off,
                                              const int* __restrict__ csr,
                                              const float* __restrict__ as2,
                                              const float* __restrict__ ad2,
                                              const u32* __restrict__ h2w,
                                              const float* __restrict__ b2,
                                              float* __restrict__ outp){
  int t = threadIdx.x;
  int node = blockIdx.x*32 + (t >> 3);
  int c2 = t & 7;                        // channels 2*c2, 2*c2+1
  if(node >= N) return;
  int beg = off[node], end = off[node+1];
  float adv = ad2[node];
  float den = 0.f, num0 = 0.f, num1 = 0.f;
  for(int base = beg; base < end; base += 8){
    int cnt = end - base; if(cnt > 8) cnt = 8;
    float w_my = 0.f; int s_my = 0;
    if(c2 < cnt){
      s_my = csr[base + c2];
      float v = as2[s_my] + adv;
      v = v > 0.f ? v : NEG*v;
      w_my = __expf(v);
    }
    #pragma unroll
    for(int j=0; j<8; j++){
      if(j >= cnt) break;
      int src = (t & 56) | j;            // lane within wave: (wl & ~7) | j
      float w = __shfl(w_my, src);
      int   s = __shfl(s_my, src);
      u32 u = h2w[(size_t)s*8 + c2];
      den += w;
      num0 = fmaf(w, blo(u), num0);
      num1 = fmaf(w, bhi(u), num1);
    }
  }
  float inv = 1.f / (den + 1e-16f);
  float2 bb = ((const float2*)b2)[c2];
  float2 r;
  r.x = num0*inv + bb.x;
  r.y = num1*inv + bb.y;
  ((float2*)outp)[(size_t)node*8 + c2] = r;
}

extern "C" void kernel_launch(void* const* d_in, const int* in_sizes, int n_in,
                              void* d_out, int out_size, void* d_ws, size_t ws_size,
                              hipStream_t stream){
  const float* x     = (const float*)d_in[0];
  const int*   ei    = (const int*)  d_in[1];
  const float* W1    = (const float*)d_in[2];
  const float* av_s1 = (const float*)d_in[3];
  const float* av_d1 = (const float*)d_in[4];
  const float* b1    = (const float*)d_in[5];
  const float* W2    = (const float*)d_in[6];
  const float* av_s2 = (const float*)d_in[7];
  const float* av_d2 = (const float*)d_in[8];
  const float* b2    = (const float*)d_in[9];
  float* outp = (float*)d_out;

  char* p = (char*)d_ws;
  auto alloc = [&](size_t bytes){ char* q = p; p += (bytes + 255) & ~(size_t)255; return q; };
  u16*   h1b    = (u16*)  alloc((size_t)N*HH*2);
  u16*   helu_b = (u16*)  alloc((size_t)N*HH*2);
  u16*   h2b    = (u16*)  alloc((size_t)N*CLS*2);
  float* as1    = (float*)alloc((size_t)N*HEADS*4);
  float* ad1    = (float*)alloc((size_t)N*HEADS*4);
  float* as2    = (float*)alloc((size_t)N*4);
  float* ad2    = (float*)alloc((size_t)N*4);
  int*   deg    = (int*)  alloc((size_t)N*4);
  int*   head   = (int*)  alloc((size_t)N*4);
  int*   off    = (int*)  alloc((size_t)(N+1)*4);
  int*   csr    = (int*)  alloc((size_t)ETOT*4);
  u64*   nsrc   = (u64*)  alloc((size_t)ETOT*8);
  int*   bsum   = (int*)  alloc((size_t)NB*4);
  int*   boff   = (int*)  alloc((size_t)NB*4);

  hipMemsetAsync(deg, 0, (size_t)N*4, stream);
  hipMemsetAsync(head, 0xFF, (size_t)N*4, stream);

  // fused: GEMM1(+alpha1) and edge hist+link pass
  k_gemm1link<<<GEMM_NB + LINK_NB, 256, 0, stream>>>(x, W1, av_s1, av_d1, h1b, as1, ad1,
                                                     ei, deg, head, nsrc);
  // CSR offsets + walk-fill
  k_scan1<<<NB, 256, 0, stream>>>(deg, bsum);
  k_scan2<<<1, 256, 0, stream>>>(bsum, boff, off);
  k_scan3walk<<<NB, 256, 0, stream>>>(deg, boff, head, nsrc, off, csr);

  // layer 1 aggregation
  k_agg1<<<N/4, 256, 0, stream>>>(off, csr, as1, ad1, (const u32*)h1b, b1, (u32*)helu_b);

  // layer 2
  k_gemm2<<<(N+15)/16, 256, 0, stream>>>(helu_b, W2, av_s2, av_d2, h2b, as2, ad2);
  k_agg2<<<(N+31)/32, 256, 0, stream>>>(off, csr, as2, ad2, (const u32*)h2b, b2, outp);
}

// Round 9
// 171.059 us; speedup vs baseline: 1.5687x; 1.0081x over previous
//
#include <hip/hip_runtime.h>
#include <hip/hip_bf16.h>
#include <limits.h>
#include <math.h>

#define N 50000
#define E_ 800000
#define ETOT 850000          // E + N self loops
#define HH 128               // HEADS*HID
#define HEADS 8
#define HID 16
#define CLS 16
#define NEG 0.2f
#define NB ((N + 255) / 256) // 196 scan blocks

typedef unsigned short u16;
typedef unsigned int   u32;
typedef unsigned long long u64;
typedef short s8v __attribute__((ext_vector_type(8)));
typedef float f4v __attribute__((ext_vector_type(4)));

__device__ __forceinline__ u16 f2bu(float f){           // f32 -> bf16 RNE
  union{float f; u32 i;} c; c.f = f;
  u32 lsb = (c.i >> 16) & 1u;
  c.i += 0x7fffu + lsb;
  return (u16)(c.i >> 16);
}
__device__ __forceinline__ float bu2f(u16 u){           // bf16 -> f32
  union{u32 i; float f;} c; c.i = ((u32)u) << 16; return c.f;
}
__device__ __forceinline__ float blo(u32 u){ union{u32 i; float f;} c; c.i = u << 16; return c.f; }
__device__ __forceinline__ float bhi(u32 u){ union{u32 i; float f;} c; c.i = u & 0xffff0000u; return c.f; }

// ---------------- W1 pre-split (hi/lo bf16) + transpose: wt[c][k] ----------------
__global__ __launch_bounds__(256) void k_prepW(const float* __restrict__ W,
                                               u16* __restrict__ wth, u16* __restrict__ wtl){
  int i = blockIdx.x*256 + threadIdx.x;
  if(i >= 128*128) return;
  int k = i >> 7, c = i & 127;
  float v = W[i];                      // W[k][c]
  u16 hi = f2bu(v);
  u16 lo = f2bu(v - bu2f(hi));
  wth[c*128 + k] = hi;
  wtl[c*128 + k] = lo;
}

// ---------------- edge pass: linked-list build (1 atomic/edge) ----------------
__global__ __launch_bounds__(256) void k_link(const int* __restrict__ ei,
                                              int* __restrict__ head,
                                              int* __restrict__ srcv,
                                              int* __restrict__ nxt){
  int e = blockIdx.x*256 + threadIdx.x;
  if(e >= ETOT) return;
  int s, d;
  if(e < E_){ s = ei[e]; d = ei[E_ + e]; } else { s = d = e - E_; }
  int old = atomicExch(&head[d], e);
  srcv[e] = s;
  nxt[e]  = old;
}

// ---------------- MFMA split-bf16 GEMM1: h1b[N,128] = x @ W1 (≈f32 exact) ----------------
#define GBM 64
__global__ __launch_bounds__(256) void k_gemm1m(const float* __restrict__ x,
                                                const u16* __restrict__ wth,
                                                const u16* __restrict__ wtl,
                                                u16* __restrict__ h1b){
  __shared__ u16 xh[GBM][40], xl[GBM][40];     // pad-40: 2-way bank alias (free)
  __shared__ u16 wh[128][40], wl[128][40];
  int tid  = threadIdx.x;
  int wv   = tid >> 6;
  int lane = tid & 63;
  int row0 = blockIdx.x * GBM;

  f4v acc[4][2];
  #pragma unroll
  for(int t=0;t<4;t++)
    #pragma unroll
    for(int u=0;u<2;u++) acc[t][u] = (f4v){0.f,0.f,0.f,0.f};

  int xr  = tid >> 2;                 // staging row 0..63
  int xkq = (tid & 3) * 8;            // staging k offset
  int wc  = tid & 127;                // staging col
  int wq  = (tid >> 7) * 8;           // 0 or 8
  int xrow = row0 + xr; if(xrow >= N) xrow = N-1;
  const float* xb = x + (size_t)xrow*128 + xkq;
  int fr = lane & 15, fg = lane >> 4;
  int kk = fg*8;

  for(int kc=0; kc<4; kc++){
    int k0 = kc*32;
    float4 v0 = *(const float4*)(xb + k0);
    float4 v1 = *(const float4*)(xb + k0 + 4);
    __syncthreads();                  // previous chunk's frag reads done
    {
      float vv[8] = {v0.x,v0.y,v0.z,v0.w,v1.x,v1.y,v1.z,v1.w};
      s8v H, L;
      #pragma unroll
      for(int j=0;j<8;j++){
        u16 h_ = f2bu(vv[j]);
        H[j] = (short)h_;
        L[j] = (short)f2bu(vv[j] - bu2f(h_));
      }
      *(s8v*)&xh[xr][xkq] = H;
      *(s8v*)&xl[xr][xkq] = L;
    }
    #pragma unroll
    for(int j=0;j<2;j++){
      int kq = wq + j*16;
      *(s8v*)&wh[wc][kq] = *(const s8v*)&wth[wc*128 + k0 + kq];
      *(s8v*)&wl[wc][kq] = *(const s8v*)&wtl[wc*128 + k0 + kq];
    }
    __syncthreads();
    s8v a_h[4], a_l[4], b_h[2], b_l[2];
    #pragma unroll
    for(int t=0;t<4;t++){
      a_h[t] = *(const s8v*)&xh[t*16 + fr][kk];
      a_l[t] = *(const s8v*)&xl[t*16 + fr][kk];
    }
    #pragma unroll
    for(int u=0;u<2;u++){
      int col = wv*32 + u*16 + fr;
      b_h[u] = *(const s8v*)&wh[col][kk];
      b_l[u] = *(const s8v*)&wl[col][kk];
    }
    #pragma unroll
    for(int t=0;t<4;t++){
      #pragma unroll
      for(int u=0;u<2;u++){
        acc[t][u] = __builtin_amdgcn_mfma_f32_16x16x32_bf16(a_h[t], b_h[u], acc[t][u], 0,0,0);
        acc[t][u] = __builtin_amdgcn_mfma_f32_16x16x32_bf16(a_h[t], b_l[u], acc[t][u], 0,0,0);
        acc[t][u] = __builtin_amdgcn_mfma_f32_16x16x32_bf16(a_l[t], b_h[u], acc[t][u], 0,0,0);
      }
    }
  }
  // D layout: row = t*16 + fg*4 + j, col = wv*32 + u*16 + fr   [m89-verified]
  #pragma unroll
  for(int t=0;t<4;t++){
    #pragma unroll
    for(int j=0;j<4;j++){
      int row = row0 + t*16 + fg*4 + j;
      if(row < N){
        u16* dst = h1b + (size_t)row*128 + wv*32 + fr;
        dst[0]  = f2bu(acc[t][0][j]);
        dst[16] = f2bu(acc[t][1][j]);
      }
    }
  }
}

// ---------------- alpha1 from bf16 h1 ----------------
__global__ __launch_bounds__(256) void k_alpha1(const u16* __restrict__ h1b,
                                                const float* __restrict__ Asv,
                                                const float* __restrict__ Adv,
                                                float* __restrict__ as1,
                                                float* __restrict__ ad1){
  int id = blockIdx.x*256 + threadIdx.x;
  if(id >= N*HEADS) return;
  int i = id >> 3, h = id & 7;
  const uint4* hv = (const uint4*)(h1b + (size_t)i*HH + h*HID);
  uint4 u0 = hv[0], u1 = hv[1];
  float vals[16] = {blo(u0.x),bhi(u0.x),blo(u0.y),bhi(u0.y),
                    blo(u0.z),bhi(u0.z),blo(u0.w),bhi(u0.w),
                    blo(u1.x),bhi(u1.x),blo(u1.y),bhi(u1.y),
                    blo(u1.z),bhi(u1.z),blo(u1.w),bhi(u1.w)};
  float s=0.f, d=0.f;
  #pragma unroll
  for(int j=0;j<16;j++){
    s = fmaf(vals[j], Asv[h*HID+j], s);
    d = fmaf(vals[j], Adv[h*HID+j], d);
  }
  as1[id]=s; ad1[id]=d;
}

// ---------------- scan stage 1: degree via list walk + block sum ----------------
__global__ __launch_bounds__(256) void k_scan1walk(const int* __restrict__ head,
                                                   const int* __restrict__ nxt,
                                                   int* __restrict__ deg,
                                                   int* __restrict__ bsum){
  __shared__ int sm[256];
  int t = threadIdx.x;
  int i = blockIdx.x*256 + t;
  int cnt = 0;
  if(i < N){
    int e = head[i];
    while(e >= 0){ cnt++; e = nxt[e]; }
    deg[i] = cnt;
  }
  sm[t] = cnt;
  __syncthreads();
  #pragma unroll
  for(int ofs=128; ofs>0; ofs>>=1){
    if(t < ofs) sm[t] += sm[t+ofs];
    __syncthreads();
  }
  if(t == 0) bsum[blockIdx.x] = sm[0];
}

__global__ __launch_bounds__(256) void k_scan2(const int* __restrict__ bsum,
                                               int* __restrict__ boff,
                                               int* __restrict__ off){
  __shared__ int sm[256];
  int t = threadIdx.x;
  sm[t] = (t < NB) ? bsum[t] : 0;
  __syncthreads();
  #pragma unroll
  for(int ofs=1; ofs<256; ofs<<=1){
    int v = sm[t];
    int add = (t >= ofs) ? sm[t-ofs] : 0;
    __syncthreads();
    sm[t] = v + add;
    __syncthreads();
  }
  if(t < NB) boff[t] = (t == 0) ? 0 : sm[t-1];
  if(t == 255) off[N] = sm[NB-1];
}

// stage 3 + list walk: off[] + sequential per-node CSR fill
__global__ __launch_bounds__(256) void k_scan3walk(const int* __restrict__ deg,
                                                   const int* __restrict__ boff,
                                                   const int* __restrict__ head,
                                                   const int* __restrict__ srcv,
                                                   const int* __restrict__ nxt,
                                                   int* __restrict__ off,
                                                   int* __restrict__ csr){
  __shared__ int sm[256];
  int t = threadIdx.x;
  int i = blockIdx.x*256 + t;
  int v0 = (i < N) ? deg[i] : 0;
  sm[t] = v0;
  __syncthreads();
  #pragma unroll
  for(int ofs=1; ofs<256; ofs<<=1){
    int v = sm[t];
    int add = (t >= ofs) ? sm[t-ofs] : 0;
    __syncthreads();
    sm[t] = v + add;
    __syncthreads();
  }
  if(i < N){
    int excl = boff[blockIdx.x] + sm[t] - v0;
    off[i] = excl;
    int e = head[i];
    int pos = excl;
    while(e >= 0){
      csr[pos++] = srcv[e];
      e = nxt[e];
    }
  }
}

// ---------------- fused layer-1 aggregation: 1 wave/node, u32 loads ----------------
#define CH 32
__global__ __launch_bounds__(256) void k_agg1(const int* __restrict__ off,
                                              const int* __restrict__ csr,
                                              const float* __restrict__ as1,
                                              const float* __restrict__ ad1,
                                              const u32* __restrict__ h1w,
                                              const float* __restrict__ b1,
                                              u32* __restrict__ helu_w){
  __shared__ float wsm[4][CH*8];
  __shared__ int   ssm[4][CH];
  int wv   = threadIdx.x >> 6;
  int lane = threadIdx.x & 63;
  int node = blockIdx.x*4 + wv;          // grid = N/4 exactly
  int beg = off[node], end = off[node+1];
  int h  = lane >> 3;                    // head (channels 2*lane, 2*lane+1)
  int hh = lane & 7;                     // phase-A head
  int el = lane >> 3;                    // phase-A edge slot
  float advA = ad1[node*8 + hh];
  float den = 0.f, num0 = 0.f, num1 = 0.f;
  float* wsw = wsm[wv];
  int*   ssw = ssm[wv];
  for(int base = beg; base < end; base += CH){
    int cnt = end - base; if(cnt > CH) cnt = CH;
    #pragma unroll
    for(int k=0;k<CH;k+=8){
      int e = el + k;
      if(e < cnt){
        int s = csr[base+e];
        if(hh == 0) ssw[e] = s;
        float v = as1[s*8+hh] + advA;
        v = v > 0.f ? v : NEG*v;
        wsw[e*8+hh] = __expf(v);         // shift-invariant softmax; logits bounded
      }
    }
    int e = 0;
    for(; e+4 <= cnt; e += 4){
      int s0 = ssw[e], s1 = ssw[e+1], s2 = ssw[e+2], s3 = ssw[e+3];
      float w0 = wsw[e*8+h], w1 = wsw[e*8+8+h], w2 = wsw[e*8+16+h], w3 = wsw[e*8+24+h];
      u32 u0 = h1w[(size_t)s0*64 + lane];
      u32 u1 = h1w[(size_t)s1*64 + lane];
      u32 u2 = h1w[(size_t)s2*64 + lane];
      u32 u3 = h1w[(size_t)s3*64 + lane];
      den += (w0+w1)+(w2+w3);
      num0 = fmaf(w0, blo(u0), num0); num1 = fmaf(w0, bhi(u0), num1);
      num0 = fmaf(w1, blo(u1), num0); num1 = fmaf(w1, bhi(u1), num1);
      num0 = fmaf(w2, blo(u2), num0); num1 = fmaf(w2, bhi(u2), num1);
      num0 = fmaf(w3, blo(u3), num0); num1 = fmaf(w3, bhi(u3), num1);
    }
    for(; e < cnt; e++){
      int s = ssw[e];
      float w = wsw[e*8+h];
      u32 u = h1w[(size_t)s*64 + lane];
      den += w;
      num0 = fmaf(w, blo(u), num0);
      num1 = fmaf(w, bhi(u), num1);
    }
  }
  float2 bb = ((const float2*)b1)[lane];
  float inv = 1.f / (den + 1e-16f);
  float r0 = num0*inv + bb.x;
  float r1 = num1*inv + bb.y;
  r0 = r0 > 0.f ? r0 : expm1f(r0);
  r1 = r1 > 0.f ? r1 : expm1f(r1);
  helu_w[(size_t)node*64 + lane] = (u32)f2bu(r0) | ((u32)f2bu(r1) << 16);
}

// ---------------- GEMM2 (bf16 in) + fused alpha2; h2 stored bf16 ----------------
__global__ __launch_bounds__(256) void k_gemm2(const u16* __restrict__ hb,
                                               const float* __restrict__ W2,
                                               const float* __restrict__ Asv,
                                               const float* __restrict__ Adv,
                                               u16* __restrict__ h2b,
                                               float* __restrict__ as2,
                                               float* __restrict__ ad2){
  __shared__ float Wl[128*16];
  int tid = threadIdx.x;
  const float4* W4 = (const float4*)W2;
  float4* Wl4 = (float4*)Wl;
  Wl4[tid]       = W4[tid];
  Wl4[tid + 256] = W4[tid + 256];
  __syncthreads();
  int i = blockIdx.x*16 + (tid >> 4);
  int c = tid & 15;
  if(i >= N) return;
  const uint4* h8 = (const uint4*)(hb + (size_t)i*HH);
  float acc = 0.f;
  #pragma unroll
  for(int ch=0; ch<16; ch++){
    uint4 u = h8[ch];
    int k = ch*8;
    acc = fmaf(blo(u.x), Wl[(k+0)*16+c], acc);
    acc = fmaf(bhi(u.x), Wl[(k+1)*16+c], acc);
    acc = fmaf(blo(u.y), Wl[(k+2)*16+c], acc);
    acc = fmaf(bhi(u.y), Wl[(k+3)*16+c], acc);
    acc = fmaf(blo(u.z), Wl[(k+4)*16+c], acc);
    acc = fmaf(bhi(u.z), Wl[(k+5)*16+c], acc);
    acc = fmaf(blo(u.w), Wl[(k+6)*16+c], acc);
    acc = fmaf(bhi(u.w), Wl[(k+7)*16+c], acc);
  }
  h2b[(size_t)i*CLS + c] = f2bu(acc);
  float ps = acc * Asv[c];
  float pd = acc * Adv[c];
  ps += __shfl_xor(ps,1); ps += __shfl_xor(ps,2); ps += __shfl_xor(ps,4); ps += __shfl_xor(ps,8);
  pd += __shfl_xor(pd,1); pd += __shfl_xor(pd,2); pd += __shfl_xor(pd,4); pd += __shfl_xor(pd,8);
  if(c == 0){ as2[i] = ps; ad2[i] = pd; }
}

// ---------------- fused layer-2 aggregation: 8 lanes/node, shfl-shared exp ----------------
__global__ __launch_bounds__(256) void k_agg2(const int* __restrict__ off,
                                              const int* __restrict__ csr,
                                              const float* __restrict__ as2,
                                              const float* __restrict__ ad2,
                                              const u32* __restrict__ h2w,
                                              const float* __restrict__ b2,
                                              float* __restrict__ outp){
  int t = threadIdx.x;
  int node = blockIdx.x*32 + (t >> 3);
  int c2 = t & 7;                        // channels 2*c2, 2*c2+1
  if(node >= N) return;
  int beg = off[node], end = off[node+1];
  float adv = ad2[node];
  float den = 0.f, num0 = 0.f, num1 = 0.f;
  for(int base = beg; base < end; base += 8){
    int cnt = end - base; if(cnt > 8) cnt = 8;
    float w_my = 0.f; int s_my = 0;
    if(c2 < cnt){
      s_my = csr[base + c2];
      float v = as2[s_my] + adv;
      v = v > 0.f ? v : NEG*v;
      w_my = __expf(v);
    }
    #pragma unroll
    for(int j=0; j<8; j++){
      if(j >= cnt) break;
      int src = (t & 56) | j;            // lane within wave: (wl & ~7) | j
      float w = __shfl(w_my, src);
      int   s = __shfl(s_my, src);
      u32 u = h2w[(size_t)s*8 + c2];
      den += w;
      num0 = fmaf(w, blo(u), num0);
      num1 = fmaf(w, bhi(u), num1);
    }
  }
  float inv = 1.f / (den + 1e-16f);
  float2 bb = ((const float2*)b2)[c2];
  float2 r;
  r.x = num0*inv + bb.x;
  r.y = num1*inv + bb.y;
  ((float2*)outp)[(size_t)node*8 + c2] = r;
}

extern "C" void kernel_launch(void* const* d_in, const int* in_sizes, int n_in,
                              void* d_out, int out_size, void* d_ws, size_t ws_size,
                              hipStream_t stream){
  const float* x     = (const float*)d_in[0];
  const int*   ei    = (const int*)  d_in[1];
  const float* W1    = (const float*)d_in[2];
  const float* av_s1 = (const float*)d_in[3];
  const float* av_d1 = (const float*)d_in[4];
  const float* b1    = (const float*)d_in[5];
  const float* W2    = (const float*)d_in[6];
  const float* av_s2 = (const float*)d_in[7];
  const float* av_d2 = (const float*)d_in[8];
  const float* b2    = (const float*)d_in[9];
  float* outp = (float*)d_out;

  char* p = (char*)d_ws;
  auto alloc = [&](size_t bytes){ char* q = p; p += (bytes + 255) & ~(size_t)255; return q; };
  u16*   h1b    = (u16*)  alloc((size_t)N*HH*2);
  u16*   helu_b = (u16*)  alloc((size_t)N*HH*2);
  u16*   h2b    = (u16*)  alloc((size_t)N*CLS*2);
  float* as1    = (float*)alloc((size_t)N*HEADS*4);
  float* ad1    = (float*)alloc((size_t)N*HEADS*4);
  float* as2    = (float*)alloc((size_t)N*4);
  float* ad2    = (float*)alloc((size_t)N*4);
  int*   deg    = (int*)  alloc((size_t)N*4);
  int*   head   = (int*)  alloc((size_t)N*4);
  int*   off    = (int*)  alloc((size_t)(N+1)*4);
  int*   csr    = (int*)  alloc((size_t)ETOT*4);
  int*   srcv   = (int*)  alloc((size_t)ETOT*4);
  int*   nxt    = (int*)  alloc((size_t)ETOT*4);
  u16*   wth    = (u16*)  alloc((size_t)128*128*2);
  u16*   wtl    = (u16*)  alloc((size_t)128*128*2);
  int*   bsum   = (int*)  alloc((size_t)NB*4);
  int*   boff   = (int*)  alloc((size_t)NB*4);

  hipMemsetAsync(head, 0xFF, (size_t)N*4, stream);

  // CSR build (1 atomic/edge) + W pre-split
  k_link<<<(ETOT+255)/256, 256, 0, stream>>>(ei, head, srcv, nxt);
  k_prepW<<<(128*128+255)/256, 256, 0, stream>>>(W1, wth, wtl);

  // layer 1 GEMM (MFMA split-bf16) + alpha
  k_gemm1m<<<(N+GBM-1)/GBM, 256, 0, stream>>>(x, wth, wtl, h1b);
  k_alpha1<<<(N*HEADS+255)/256, 256, 0, stream>>>(h1b, av_s1, av_d1, as1, ad1);

  // CSR offsets + walk-fill
  k_scan1walk<<<NB, 256, 0, stream>>>(head, nxt, deg, bsum);
  k_scan2<<<1, 256, 0, stream>>>(bsum, boff, off);
  k_scan3walk<<<NB, 256, 0, stream>>>(deg, boff, head, srcv, nxt, off, csr);

  // layer 1 aggregation
  k_agg1<<<N/4, 256, 0, stream>>>(off, csr, as1, ad1, (const u32*)h1b, b1, (u32*)helu_b);

  // layer 2
  k_gemm2<<<(N+15)/16, 256, 0, stream>>>(helu_b, W2, av_s2, av_d2, h2b, as2, ad2);
  k_agg2<<<(N+31)/32, 256, 0, stream>>>(off, csr, as2, ad2, (const u32*)h2b, b2, outp);
}

// Round 10
// 160.402 us; speedup vs baseline: 1.6729x; 1.0664x over previous
//
#include <hip/hip_runtime.h>
#include <hip/hip_bf16.h>
#include <limits.h>
#include <math.h>

#define N 50000
#define E_ 800000
#define ETOT 850000          // E + N self loops
#define HH 128               // HEADS*HID
#define HEADS 8
#define HID 16
#define CLS 16
#define NEG 0.2f
#define NB ((N + 255) / 256)             // 196 scan blocks
#define GBM 64
#define GEMM_NB ((N + GBM - 1) / GBM)    // 782
#define LINK_NB ((ETOT + 255) / 256)     // 3321
#define A1_NB ((N*HEADS + 255) / 256)    // 1563

typedef unsigned short u16;
typedef unsigned int   u32;
typedef short s8v __attribute__((ext_vector_type(8)));
typedef float f4v __attribute__((ext_vector_type(4)));

__device__ __forceinline__ u16 f2bu(float f){           // f32 -> bf16 RNE
  union{float f; u32 i;} c; c.f = f;
  u32 lsb = (c.i >> 16) & 1u;
  c.i += 0x7fffu + lsb;
  return (u16)(c.i >> 16);
}
__device__ __forceinline__ float bu2f(u16 u){
  union{u32 i; float f;} c; c.i = ((u32)u) << 16; return c.f;
}
__device__ __forceinline__ float blo(u32 u){ union{u32 i; float f;} c; c.i = u << 16; return c.f; }
__device__ __forceinline__ float bhi(u32 u){ union{u32 i; float f;} c; c.i = u & 0xffff0000u; return c.f; }

// ---------------- W1 pre-split (hi/lo bf16) + transpose: wt[c][k] ----------------
__global__ __launch_bounds__(256) void k_prepW(const float* __restrict__ W,
                                               u16* __restrict__ wth, u16* __restrict__ wtl){
  int i = blockIdx.x*256 + threadIdx.x;
  if(i >= 128*128) return;
  int k = i >> 7, c = i & 127;
  float v = W[i];                      // W[k][c]
  u16 hi = f2bu(v);
  u16 lo = f2bu(v - bu2f(hi));
  wth[c*128 + k] = hi;
  wtl[c*128 + k] = lo;
}

// ---------------- fused: MFMA split-bf16 GEMM1 ∥ linked-list CSR build ----------------
__global__ __launch_bounds__(256) void k_gemm1link(const float* __restrict__ x,
                                                   const u16* __restrict__ wth,
                                                   const u16* __restrict__ wtl,
                                                   u16* __restrict__ h1b,
                                                   const int* __restrict__ ei,
                                                   int* __restrict__ head,
                                                   int* __restrict__ srcv,
                                                   int* __restrict__ nxt){
  __shared__ u16 xh[GBM][40], xl[GBM][40];     // pad-40: 2-way bank alias (free)
  __shared__ u16 wh[128][40], wl[128][40];
  if(blockIdx.x >= GEMM_NB){
    // ---- edge pass: 1 atomic/edge linked-list build, coalesced srcv/nxt ----
    int e = (blockIdx.x - GEMM_NB)*256 + threadIdx.x;
    if(e < ETOT){
      int s, d;
      if(e < E_){ s = ei[e]; d = ei[E_ + e]; } else { s = d = e - E_; }
      int old = atomicExch(&head[d], e);
      srcv[e] = s;
      nxt[e]  = old;
    }
    return;
  }
  // ---- GEMM1 ----
  int tid  = threadIdx.x;
  int wv   = tid >> 6;
  int lane = tid & 63;
  int row0 = blockIdx.x * GBM;

  f4v acc[4][2];
  #pragma unroll
  for(int t=0;t<4;t++)
    #pragma unroll
    for(int u=0;u<2;u++) acc[t][u] = (f4v){0.f,0.f,0.f,0.f};

  int xr  = tid >> 2;
  int xkq = (tid & 3) * 8;
  int wc  = tid & 127;
  int wq  = (tid >> 7) * 8;
  int xrow = row0 + xr; if(xrow >= N) xrow = N-1;
  const float* xb = x + (size_t)xrow*128 + xkq;
  int fr = lane & 15, fg = lane >> 4;
  int kk = fg*8;

  for(int kc=0; kc<4; kc++){
    int k0 = kc*32;
    float4 v0 = *(const float4*)(xb + k0);
    float4 v1 = *(const float4*)(xb + k0 + 4);
    __syncthreads();
    {
      float vv[8] = {v0.x,v0.y,v0.z,v0.w,v1.x,v1.y,v1.z,v1.w};
      s8v H, L;
      #pragma unroll
      for(int j=0;j<8;j++){
        u16 h_ = f2bu(vv[j]);
        H[j] = (short)h_;
        L[j] = (short)f2bu(vv[j] - bu2f(h_));
      }
      *(s8v*)&xh[xr][xkq] = H;
      *(s8v*)&xl[xr][xkq] = L;
    }
    #pragma unroll
    for(int j=0;j<2;j++){
      int kq = wq + j*16;
      *(s8v*)&wh[wc][kq] = *(const s8v*)&wth[wc*128 + k0 + kq];
      *(s8v*)&wl[wc][kq] = *(const s8v*)&wtl[wc*128 + k0 + kq];
    }
    __syncthreads();
    s8v a_h[4], a_l[4], b_h[2], b_l[2];
    #pragma unroll
    for(int t=0;t<4;t++){
      a_h[t] = *(const s8v*)&xh[t*16 + fr][kk];
      a_l[t] = *(const s8v*)&xl[t*16 + fr][kk];
    }
    #pragma unroll
    for(int u=0;u<2;u++){
      int col = wv*32 + u*16 + fr;
      b_h[u] = *(const s8v*)&wh[col][kk];
      b_l[u] = *(const s8v*)&wl[col][kk];
    }
    #pragma unroll
    for(int t=0;t<4;t++){
      #pragma unroll
      for(int u=0;u<2;u++){
        acc[t][u] = __builtin_amdgcn_mfma_f32_16x16x32_bf16(a_h[t], b_h[u], acc[t][u], 0,0,0);
        acc[t][u] = __builtin_amdgcn_mfma_f32_16x16x32_bf16(a_h[t], b_l[u], acc[t][u], 0,0,0);
        acc[t][u] = __builtin_amdgcn_mfma_f32_16x16x32_bf16(a_l[t], b_h[u], acc[t][u], 0,0,0);
      }
    }
  }
  // D layout: row = t*16 + fg*4 + j, col = wv*32 + u*16 + fr
  #pragma unroll
  for(int t=0;t<4;t++){
    #pragma unroll
    for(int j=0;j<4;j++){
      int row = row0 + t*16 + fg*4 + j;
      if(row < N){
        u16* dst = h1b + (size_t)row*128 + wv*32 + fr;
        dst[0]  = f2bu(acc[t][0][j]);
        dst[16] = f2bu(acc[t][1][j]);
      }
    }
  }
}

// ---------------- fused: degree list-walk + block sums ∥ alpha1 ----------------
__global__ __launch_bounds__(256) void k_alphascan1(const u16* __restrict__ h1b,
                                                    const float* __restrict__ Asv,
                                                    const float* __restrict__ Adv,
                                                    float* __restrict__ as1,
                                                    float* __restrict__ ad1,
                                                    const int* __restrict__ head,
                                                    const int* __restrict__ nxt,
                                                    int* __restrict__ deg,
                                                    int* __restrict__ bsum){
  __shared__ int sm[256];
  if(blockIdx.x < NB){
    int t = threadIdx.x;
    int i = blockIdx.x*256 + t;
    int cnt = 0;
    if(i < N){
      int e = head[i];
      while(e >= 0){ cnt++; e = nxt[e]; }
      deg[i] = cnt;
    }
    sm[t] = cnt;
    __syncthreads();
    #pragma unroll
    for(int ofs=128; ofs>0; ofs>>=1){
      if(t < ofs) sm[t] += sm[t+ofs];
      __syncthreads();
    }
    if(t == 0) bsum[blockIdx.x] = sm[0];
    return;
  }
  int id = (blockIdx.x - NB)*256 + threadIdx.x;
  if(id >= N*HEADS) return;
  int i = id >> 3, h = id & 7;
  const uint4* hv = (const uint4*)(h1b + (size_t)i*HH + h*HID);
  uint4 u0 = hv[0], u1 = hv[1];
  float vals[16] = {blo(u0.x),bhi(u0.x),blo(u0.y),bhi(u0.y),
                    blo(u0.z),bhi(u0.z),blo(u0.w),bhi(u0.w),
                    blo(u1.x),bhi(u1.x),blo(u1.y),bhi(u1.y),
                    blo(u1.z),bhi(u1.z),blo(u1.w),bhi(u1.w)};
  float s=0.f, d=0.f;
  #pragma unroll
  for(int j=0;j<16;j++){
    s = fmaf(vals[j], Asv[h*HID+j], s);
    d = fmaf(vals[j], Adv[h*HID+j], d);
  }
  as1[id]=s; ad1[id]=d;
}

// ---------------- scan3 + in-block boff reduction + list-walk CSR fill ----------------
__global__ __launch_bounds__(256) void k_scan3walk(const int* __restrict__ deg,
                                                   const int* __restrict__ bsum,
                                                   const int* __restrict__ head,
                                                   const int* __restrict__ srcv,
                                                   const int* __restrict__ nxt,
                                                   int* __restrict__ off,
                                                   int* __restrict__ csr){
  __shared__ int red[256];
  __shared__ int sm[256];
  int t = threadIdx.x;
  red[t] = (t < blockIdx.x) ? bsum[t] : 0;     // blockIdx.x <= 195 < 256
  __syncthreads();
  #pragma unroll
  for(int ofs=128; ofs>0; ofs>>=1){
    if(t < ofs) red[t] += red[t+ofs];
    __syncthreads();
  }
  int boff = red[0];
  int i = blockIdx.x*256 + t;
  int v0 = (i < N) ? deg[i] : 0;
  sm[t] = v0;
  __syncthreads();
  #pragma unroll
  for(int ofs=1; ofs<256; ofs<<=1){
    int v = sm[t];
    int add = (t >= ofs) ? sm[t-ofs] : 0;
    __syncthreads();
    sm[t] = v + add;
    __syncthreads();
  }
  if(i < N){
    int excl = boff + sm[t] - v0;
    off[i] = excl;
    if(i == N-1) off[N] = excl + v0;
    int e = head[i];
    int pos = excl;
    while(e >= 0){
      csr[pos++] = srcv[e];
      e = nxt[e];
    }
  }
}

// ---------------- fused layer-1 aggregation: 1 wave/node, CH=64, 8-deep gathers ----------------
#define CH 64
__global__ __launch_bounds__(256) void k_agg1(const int* __restrict__ off,
                                              const int* __restrict__ csr,
                                              const float* __restrict__ as1,
                                              const float* __restrict__ ad1,
                                              const u32* __restrict__ h1w,
                                              const float* __restrict__ b1,
                                              u32* __restrict__ helu_w){
  __shared__ float wsm[4][CH*8];
  __shared__ int   ssm[4][CH];
  int wv   = threadIdx.x >> 6;
  int lane = threadIdx.x & 63;
  int node = blockIdx.x*4 + wv;          // grid = N/4 exactly
  int beg = off[node], end = off[node+1];
  int h  = lane >> 3;                    // head (channels 2*lane, 2*lane+1)
  int hh = lane & 7;                     // phase-A head
  int el = lane >> 3;                    // phase-A edge slot
  float advA = ad1[node*8 + hh];
  float den = 0.f, num0 = 0.f, num1 = 0.f;
  float* wsw = wsm[wv];
  int*   ssw = ssm[wv];
  const u32* hp = h1w + lane;
  for(int base = beg; base < end; base += CH){
    int cnt = end - base; if(cnt > CH) cnt = CH;
    #pragma unroll
    for(int k=0;k<CH;k+=8){
      int e = el + k;
      if(e < cnt){
        int s = csr[base+e];
        if(hh == 0) ssw[e] = s;
        float v = as1[s*8+hh] + advA;
        v = v > 0.f ? v : NEG*v;
        wsw[e*8+hh] = __expf(v);         // shift-invariant softmax; logits bounded
      }
    }
    int e = 0;
    for(; e+8 <= cnt; e += 8){
      int ss[8]; float ww[8]; u32 uu[8];
      #pragma unroll
      for(int j=0;j<8;j++){ ss[j] = ssw[e+j]; ww[j] = wsw[(e+j)*8+h]; }
      #pragma unroll
      for(int j=0;j<8;j++){ uu[j] = hp[(size_t)ss[j]*64]; }
      #pragma unroll
      for(int j=0;j<8;j++){
        den += ww[j];
        num0 = fmaf(ww[j], blo(uu[j]), num0);
        num1 = fmaf(ww[j], bhi(uu[j]), num1);
      }
    }
    for(; e < cnt; e++){
      int s = ssw[e];
      float w = wsw[e*8+h];
      u32 u = hp[(size_t)s*64];
      den += w;
      num0 = fmaf(w, blo(u), num0);
      num1 = fmaf(w, bhi(u), num1);
    }
  }
  float2 bb = ((const float2*)b1)[lane];
  float inv = 1.f / (den + 1e-16f);
  float r0 = num0*inv + bb.x;
  float r1 = num1*inv + bb.y;
  r0 = r0 > 0.f ? r0 : expm1f(r0);
  r1 = r1 > 0.f ? r1 : expm1f(r1);
  helu_w[(size_t)node*64 + lane] = (u32)f2bu(r0) | ((u32)f2bu(r1) << 16);
}

// ---------------- GEMM2 (bf16 in) + fused alpha2; h2 stored bf16 ----------------
__global__ __launch_bounds__(256) void k_gemm2(const u16* __restrict__ hb,
                                               const float* __restrict__ W2,
                                               const float* __restrict__ Asv,
                                               const float* __restrict__ Adv,
                                               u16* __restrict__ h2b,
                                               float* __restrict__ as2,
                                               float* __restrict__ ad2){
  __shared__ float Wl[128*16];
  int tid = threadIdx.x;
  const float4* W4 = (const float4*)W2;
  float4* Wl4 = (float4*)Wl;
  Wl4[tid]       = W4[tid];
  Wl4[tid + 256] = W4[tid + 256];
  __syncthreads();
  int i = blockIdx.x*16 + (tid >> 4);
  int c = tid & 15;
  if(i >= N) return;
  const uint4* h8 = (const uint4*)(hb + (size_t)i*HH);
  float acc = 0.f;
  #pragma unroll
  for(int ch=0; ch<16; ch++){
    uint4 u = h8[ch];
    int k = ch*8;
    acc = fmaf(blo(u.x), Wl[(k+0)*16+c], acc);
    acc = fmaf(bhi(u.x), Wl[(k+1)*16+c], acc);
    acc = fmaf(blo(u.y), Wl[(k+2)*16+c], acc);
    acc = fmaf(bhi(u.y), Wl[(k+3)*16+c], acc);
    acc = fmaf(blo(u.z), Wl[(k+4)*16+c], acc);
    acc = fmaf(bhi(u.z), Wl[(k+5)*16+c], acc);
    acc = fmaf(blo(u.w), Wl[(k+6)*16+c], acc);
    acc = fmaf(bhi(u.w), Wl[(k+7)*16+c], acc);
  }
  h2b[(size_t)i*CLS + c] = f2bu(acc);
  float ps = acc * Asv[c];
  float pd = acc * Adv[c];
  ps += __shfl_xor(ps,1); ps += __shfl_xor(ps,2); ps += __shfl_xor(ps,4); ps += __shfl_xor(ps,8);
  pd += __shfl_xor(pd,1); pd += __shfl_xor(pd,2); pd += __shfl_xor(pd,4); pd += __shfl_xor(pd,8);
  if(c == 0){ as2[i] = ps; ad2[i] = pd; }
}

// ---------------- fused layer-2 aggregation: 8 lanes/node, shfl-shared exp ----------------
__global__ __launch_bounds__(256) void k_agg2(const int* __restrict__ off,
                                              const int* __restrict__ csr,
                                              const float* __restrict__ as2,
                                              const float* __restrict__ ad2,
                                              const u32* __restrict__ h2w,
                                              const float* __restrict__ b2,
                                              float* __restrict__ outp){
  int t = threadIdx.x;
  int node = blockIdx.x*32 + (t >> 3);
  int c2 = t & 7;                        // channels 2*c2, 2*c2+1
  if(node >= N) return;
  int beg = off[node], end = off[node+1];
  float adv = ad2[node];
  float den = 0.f, num0 = 0.f, num1 = 0.f;
  for(int base = beg; base < end; base += 8){
    int cnt = end - base; if(cnt > 8) cnt = 8;
    float w_my = 0.f; int s_my = 0;
    if(c2 < cnt){
      s_my = csr[base + c2];
      float v = as2[s_my] + adv;
      v = v > 0.f ? v : NEG*v;
      w_my = __expf(v);
    }
    #pragma unroll
    for(int j=0; j<8; j++){
      if(j >= cnt) break;
      int src = (t & 56) | j;
      float w = __shfl(w_my, src);
      int   s = __shfl(s_my, src);
      u32 u = h2w[(size_t)s*8 + c2];
      den += w;
      num0 = fmaf(w, blo(u), num0);
      num1 = fmaf(w, bhi(u), num1);
    }
  }
  float inv = 1.f / (den + 1e-16f);
  float2 bb = ((const float2*)b2)[c2];
  float2 r;
  r.x = num0*inv + bb.x;
  r.y = num1*inv + bb.y;
  ((float2*)outp)[(size_t)node*8 + c2] = r;
}

extern "C" void kernel_launch(void* const* d_in, const int* in_sizes, int n_in,
                              void* d_out, int out_size, void* d_ws, size_t ws_size,
                              hipStream_t stream){
  const float* x     = (const float*)d_in[0];
  const int*   ei    = (const int*)  d_in[1];
  const float* W1    = (const float*)d_in[2];
  const float* av_s1 = (const float*)d_in[3];
  const float* av_d1 = (const float*)d_in[4];
  const float* b1    = (const float*)d_in[5];
  const float* W2    = (const float*)d_in[6];
  const float* av_s2 = (const float*)d_in[7];
  const float* av_d2 = (const float*)d_in[8];
  const float* b2    = (const float*)d_in[9];
  float* outp = (float*)d_out;

  char* p = (char*)d_ws;
  auto alloc = [&](size_t bytes){ char* q = p; p += (bytes + 255) & ~(size_t)255; return q; };
  u16*   h1b    = (u16*)  alloc((size_t)N*HH*2);
  u16*   helu_b = (u16*)  alloc((size_t)N*HH*2);
  u16*   h2b    = (u16*)  alloc((size_t)N*CLS*2);
  float* as1    = (float*)alloc((size_t)N*HEADS*4);
  float* ad1    = (float*)alloc((size_t)N*HEADS*4);
  float* as2    = (float*)alloc((size_t)N*4);
  float* ad2    = (float*)alloc((size_t)N*4);
  int*   deg    = (int*)  alloc((size_t)N*4);
  int*   head   = (int*)  alloc((size_t)N*4);
  int*   off    = (int*)  alloc((size_t)(N+1)*4);
  int*   csr    = (int*)  alloc((size_t)ETOT*4);
  int*   srcv   = (int*)  alloc((size_t)ETOT*4);
  int*   nxt    = (int*)  alloc((size_t)ETOT*4);
  u16*   wth    = (u16*)  alloc((size_t)128*128*2);
  u16*   wtl    = (u16*)  alloc((size_t)128*128*2);
  int*   bsum   = (int*)  alloc((size_t)NB*4);

  hipMemsetAsync(head, 0xFF, (size_t)N*4, stream);

  // W pre-split (dependency of gemm blocks)
  k_prepW<<<(128*128+255)/256, 256, 0, stream>>>(W1, wth, wtl);

  // fused: MFMA GEMM1 ∥ linked-list build
  k_gemm1link<<<GEMM_NB + LINK_NB, 256, 0, stream>>>(x, wth, wtl, h1b, ei, head, srcv, nxt);

  // fused: degree walk + block sums ∥ alpha1
  k_alphascan1<<<NB + A1_NB, 256, 0, stream>>>(h1b, av_s1, av_d1, as1, ad1, head, nxt, deg, bsum);

  // offsets (in-block boff reduce) + CSR walk-fill
  k_scan3walk<<<NB, 256, 0, stream>>>(deg, bsum, head, srcv, nxt, off, csr);

  // layer 1 aggregation
  k_agg1<<<N/4, 256, 0, stream>>>(off, csr, as1, ad1, (const u32*)h1b, b1, (u32*)helu_b);

  // layer 2
  k_gemm2<<<(N+15)/16, 256, 0, stream>>>(helu_b, W2, av_s2, av_d2, h2b, as2, ad2);
  k_agg2<<<(N+31)/32, 256, 0, stream>>>(off, csr, as2, ad2, (const u32*)h2b, b2, outp);
}

// Round 11
// 147.814 us; speedup vs baseline: 1.8154x; 1.0852x over previous
//
#include <hip/hip_runtime.h>
#include <hip/hip_bf16.h>
#include <limits.h>
#include <math.h>

#define N 50000
#define E_ 800000
#define ETOT 850000          // E + N self loops
#define HH 128               // HEADS*HID
#define HEADS 8
#define HID 16
#define CLS 16
#define NEG 0.2f
#define NB ((N + 255) / 256)             // 196 scan blocks
#define GBM 64
#define GEMM_NB ((N + GBM - 1) / GBM)    // 782
#define LINK_NB ((ETOT + 255) / 256)     // 3321
#define A1_NB ((N*HEADS + 255) / 256)    // 1563

typedef unsigned short u16;
typedef unsigned int   u32;
typedef short s8v __attribute__((ext_vector_type(8)));
typedef float f4v __attribute__((ext_vector_type(4)));

__device__ __forceinline__ u16 f2bu(float f){           // f32 -> bf16 RNE
  union{float f; u32 i;} c; c.f = f;
  u32 lsb = (c.i >> 16) & 1u;
  c.i += 0x7fffu + lsb;
  return (u16)(c.i >> 16);
}
__device__ __forceinline__ float bu2f(u16 u){
  union{u32 i; float f;} c; c.i = ((u32)u) << 16; return c.f;
}
__device__ __forceinline__ float blo(u32 u){ union{u32 i; float f;} c; c.i = u << 16; return c.f; }
__device__ __forceinline__ float bhi(u32 u){ union{u32 i; float f;} c; c.i = u & 0xffff0000u; return c.f; }

// ---------------- W1+W2 pre-split (hi/lo bf16) + transpose ----------------
__global__ __launch_bounds__(256) void k_prep(const float* __restrict__ W1,
                                              const float* __restrict__ W2,
                                              u16* __restrict__ wth, u16* __restrict__ wtl,
                                              u16* __restrict__ w2th, u16* __restrict__ w2tl){
  int i = blockIdx.x*256 + threadIdx.x;
  if(i < 128*128){
    int k = i >> 7, c = i & 127;
    float v = W1[i];                   // W1[k][c]
    u16 hi = f2bu(v);
    wth[c*128 + k] = hi;
    wtl[c*128 + k] = f2bu(v - bu2f(hi));
  }
  if(i < 128*16){
    int k = i >> 4, c = i & 15;
    float v = W2[i];                   // W2[k][c]
    u16 hi = f2bu(v);
    w2th[c*128 + k] = hi;
    w2tl[c*128 + k] = f2bu(v - bu2f(hi));
  }
}

// ---------------- fused: MFMA split-bf16 GEMM1 ∥ linked-list CSR build ----------------
__global__ __launch_bounds__(256) void k_gemm1link(const float* __restrict__ x,
                                                   const u16* __restrict__ wth,
                                                   const u16* __restrict__ wtl,
                                                   u16* __restrict__ h1b,
                                                   const int* __restrict__ ei,
                                                   int* __restrict__ head,
                                                   int* __restrict__ srcv,
                                                   int* __restrict__ nxt){
  __shared__ u16 xh[GBM][40], xl[GBM][40];     // pad-40: 2-way bank alias (free)
  __shared__ u16 wh[128][40], wl[128][40];
  if(blockIdx.x >= GEMM_NB){
    int e = (blockIdx.x - GEMM_NB)*256 + threadIdx.x;
    if(e < ETOT){
      int s, d;
      if(e < E_){ s = ei[e]; d = ei[E_ + e]; } else { s = d = e - E_; }
      int old = atomicExch(&head[d], e);
      srcv[e] = s;
      nxt[e]  = old;
    }
    return;
  }
  int tid  = threadIdx.x;
  int wv   = tid >> 6;
  int lane = tid & 63;
  int row0 = blockIdx.x * GBM;

  f4v acc[4][2];
  #pragma unroll
  for(int t=0;t<4;t++)
    #pragma unroll
    for(int u=0;u<2;u++) acc[t][u] = (f4v){0.f,0.f,0.f,0.f};

  int xr  = tid >> 2;
  int xkq = (tid & 3) * 8;
  int wc  = tid & 127;
  int wq  = (tid >> 7) * 8;
  int xrow = row0 + xr; if(xrow >= N) xrow = N-1;
  const float* xb = x + (size_t)xrow*128 + xkq;
  int fr = lane & 15, fg = lane >> 4;
  int kk = fg*8;

  for(int kc=0; kc<4; kc++){
    int k0 = kc*32;
    float4 v0 = *(const float4*)(xb + k0);
    float4 v1 = *(const float4*)(xb + k0 + 4);
    __syncthreads();
    {
      float vv[8] = {v0.x,v0.y,v0.z,v0.w,v1.x,v1.y,v1.z,v1.w};
      s8v H, L;
      #pragma unroll
      for(int j=0;j<8;j++){
        u16 h_ = f2bu(vv[j]);
        H[j] = (short)h_;
        L[j] = (short)f2bu(vv[j] - bu2f(h_));
      }
      *(s8v*)&xh[xr][xkq] = H;
      *(s8v*)&xl[xr][xkq] = L;
    }
    #pragma unroll
    for(int j=0;j<2;j++){
      int kq = wq + j*16;
      *(s8v*)&wh[wc][kq] = *(const s8v*)&wth[wc*128 + k0 + kq];
      *(s8v*)&wl[wc][kq] = *(const s8v*)&wtl[wc*128 + k0 + kq];
    }
    __syncthreads();
    s8v a_h[4], a_l[4], b_h[2], b_l[2];
    #pragma unroll
    for(int t=0;t<4;t++){
      a_h[t] = *(const s8v*)&xh[t*16 + fr][kk];
      a_l[t] = *(const s8v*)&xl[t*16 + fr][kk];
    }
    #pragma unroll
    for(int u=0;u<2;u++){
      int col = wv*32 + u*16 + fr;
      b_h[u] = *(const s8v*)&wh[col][kk];
      b_l[u] = *(const s8v*)&wl[col][kk];
    }
    #pragma unroll
    for(int t=0;t<4;t++){
      #pragma unroll
      for(int u=0;u<2;u++){
        acc[t][u] = __builtin_amdgcn_mfma_f32_16x16x32_bf16(a_h[t], b_h[u], acc[t][u], 0,0,0);
        acc[t][u] = __builtin_amdgcn_mfma_f32_16x16x32_bf16(a_h[t], b_l[u], acc[t][u], 0,0,0);
        acc[t][u] = __builtin_amdgcn_mfma_f32_16x16x32_bf16(a_l[t], b_h[u], acc[t][u], 0,0,0);
      }
    }
  }
  // D layout: row = t*16 + fg*4 + j, col = wv*32 + u*16 + fr
  #pragma unroll
  for(int t=0;t<4;t++){
    #pragma unroll
    for(int j=0;j<4;j++){
      int row = row0 + t*16 + fg*4 + j;
      if(row < N){
        u16* dst = h1b + (size_t)row*128 + wv*32 + fr;
        dst[0]  = f2bu(acc[t][0][j]);
        dst[16] = f2bu(acc[t][1][j]);
      }
    }
  }
}

// ---------------- fused: degree list-walk + block sums ∥ alpha1 ----------------
__global__ __launch_bounds__(256) void k_alphascan1(const u16* __restrict__ h1b,
                                                    const float* __restrict__ Asv,
                                                    const float* __restrict__ Adv,
                                                    float* __restrict__ as1,
                                                    float* __restrict__ ad1,
                                                    const int* __restrict__ head,
                                                    const int* __restrict__ nxt,
                                                    int* __restrict__ deg,
                                                    int* __restrict__ bsum){
  __shared__ int sm[256];
  if(blockIdx.x < NB){
    int t = threadIdx.x;
    int i = blockIdx.x*256 + t;
    int cnt = 0;
    if(i < N){
      int e = head[i];
      while(e >= 0){ cnt++; e = nxt[e]; }
      deg[i] = cnt;
    }
    sm[t] = cnt;
    __syncthreads();
    #pragma unroll
    for(int ofs=128; ofs>0; ofs>>=1){
      if(t < ofs) sm[t] += sm[t+ofs];
      __syncthreads();
    }
    if(t == 0) bsum[blockIdx.x] = sm[0];
    return;
  }
  int id = (blockIdx.x - NB)*256 + threadIdx.x;
  if(id >= N*HEADS) return;
  int i = id >> 3, h = id & 7;
  const uint4* hv = (const uint4*)(h1b + (size_t)i*HH + h*HID);
  uint4 u0 = hv[0], u1 = hv[1];
  float vals[16] = {blo(u0.x),bhi(u0.x),blo(u0.y),bhi(u0.y),
                    blo(u0.z),bhi(u0.z),blo(u0.w),bhi(u0.w),
                    blo(u1.x),bhi(u1.x),blo(u1.y),bhi(u1.y),
                    blo(u1.z),bhi(u1.z),blo(u1.w),bhi(u1.w)};
  float s=0.f, d=0.f;
  #pragma unroll
  for(int j=0;j<16;j++){
    s = fmaf(vals[j], Asv[h*HID+j], s);
    d = fmaf(vals[j], Adv[h*HID+j], d);
  }
  as1[id]=s; ad1[id]=d;
}

// ---------------- scan3 + in-block boff reduction + list-walk CSR fill ----------------
__global__ __launch_bounds__(256) void k_scan3walk(const int* __restrict__ deg,
                                                   const int* __restrict__ bsum,
                                                   const int* __restrict__ head,
                                                   const int* __restrict__ srcv,
                                                   const int* __restrict__ nxt,
                                                   int* __restrict__ off,
                                                   int* __restrict__ csr){
  __shared__ int red[256];
  __shared__ int sm[256];
  int t = threadIdx.x;
  red[t] = (t < blockIdx.x) ? bsum[t] : 0;     // blockIdx.x <= 195 < 256
  __syncthreads();
  #pragma unroll
  for(int ofs=128; ofs>0; ofs>>=1){
    if(t < ofs) red[t] += red[t+ofs];
    __syncthreads();
  }
  int boff = red[0];
  int i = blockIdx.x*256 + t;
  int v0 = (i < N) ? deg[i] : 0;
  sm[t] = v0;
  __syncthreads();
  #pragma unroll
  for(int ofs=1; ofs<256; ofs<<=1){
    int v = sm[t];
    int add = (t >= ofs) ? sm[t-ofs] : 0;
    __syncthreads();
    sm[t] = v + add;
    __syncthreads();
  }
  if(i < N){
    int excl = boff + sm[t] - v0;
    off[i] = excl;
    if(i == N-1) off[N] = excl + v0;
    int e = head[i];
    int pos = excl;
    while(e >= 0){
      csr[pos++] = srcv[e];
      e = nxt[e];
    }
  }
}

// ---------------- fused layer-1 aggregation: 1 wave/node, CH=32, 8-deep gathers ----------------
#define CH 32
__global__ __launch_bounds__(256) void k_agg1(const int* __restrict__ off,
                                              const int* __restrict__ csr,
                                              const float* __restrict__ as1,
                                              const float* __restrict__ ad1,
                                              const u32* __restrict__ h1w,
                                              const float* __restrict__ b1,
                                              u32* __restrict__ helu_w){
  __shared__ float wsm[4][CH*8];
  __shared__ int   ssm[4][CH];
  int wv   = threadIdx.x >> 6;
  int lane = threadIdx.x & 63;
  int node = blockIdx.x*4 + wv;          // grid = N/4 exactly
  int beg = off[node], end = off[node+1];
  int h  = lane >> 3;                    // head (channels 2*lane, 2*lane+1)
  int hh = lane & 7;                     // phase-A head
  int el = lane >> 3;                    // phase-A edge slot
  float advA = ad1[node*8 + hh];
  float den = 0.f, num0 = 0.f, num1 = 0.f;
  float* wsw = wsm[wv];
  int*   ssw = ssm[wv];
  const u32* hp = h1w + lane;
  for(int base = beg; base < end; base += CH){
    int cnt = end - base; if(cnt > CH) cnt = CH;
    #pragma unroll
    for(int k=0;k<CH;k+=8){
      int e = el + k;
      if(e < cnt){
        int s = csr[base+e];
        if(hh == 0) ssw[e] = s;
        float v = as1[s*8+hh] + advA;
        v = v > 0.f ? v : NEG*v;
        wsw[e*8+hh] = __expf(v);         // shift-invariant softmax; logits bounded
      }
    }
    int e = 0;
    for(; e+8 <= cnt; e += 8){
      int ss[8]; float ww[8]; u32 uu[8];
      #pragma unroll
      for(int j=0;j<8;j++){ ss[j] = ssw[e+j]; ww[j] = wsw[(e+j)*8+h]; }
      #pragma unroll
      for(int j=0;j<8;j++){ uu[j] = hp[(size_t)ss[j]*64]; }
      #pragma unroll
      for(int j=0;j<8;j++){
        den += ww[j];
        num0 = fmaf(ww[j], blo(uu[j]), num0);
        num1 = fmaf(ww[j], bhi(uu[j]), num1);
      }
    }
    for(; e+4 <= cnt; e += 4){
      int ss[4]; float ww[4]; u32 uu[4];
      #pragma unroll
      for(int j=0;j<4;j++){ ss[j] = ssw[e+j]; ww[j] = wsw[(e+j)*8+h]; }
      #pragma unroll
      for(int j=0;j<4;j++){ uu[j] = hp[(size_t)ss[j]*64]; }
      #pragma unroll
      for(int j=0;j<4;j++){
        den += ww[j];
        num0 = fmaf(ww[j], blo(uu[j]), num0);
        num1 = fmaf(ww[j], bhi(uu[j]), num1);
      }
    }
    for(; e < cnt; e++){
      int s = ssw[e];
      float w = wsw[e*8+h];
      u32 u = hp[(size_t)s*64];
      den += w;
      num0 = fmaf(w, blo(u), num0);
      num1 = fmaf(w, bhi(u), num1);
    }
  }
  float2 bb = ((const float2*)b1)[lane];
  float inv = 1.f / (den + 1e-16f);
  float r0 = num0*inv + bb.x;
  float r1 = num1*inv + bb.y;
  r0 = r0 > 0.f ? r0 : expm1f(r0);
  r1 = r1 > 0.f ? r1 : expm1f(r1);
  helu_w[(size_t)node*64 + lane] = (u32)f2bu(r0) | ((u32)f2bu(r1) << 16);
}

// ---------------- MFMA GEMM2: h2[N,16] = helu(bf16) @ W2 (split) + fused alpha2 ----------------
__global__ __launch_bounds__(256) void k_gemm2m(const u16* __restrict__ helu,
                                                const u16* __restrict__ w2th,
                                                const u16* __restrict__ w2tl,
                                                const float* __restrict__ Asv,
                                                const float* __restrict__ Adv,
                                                u16* __restrict__ h2b,
                                                float* __restrict__ as2,
                                                float* __restrict__ ad2){
  __shared__ u16 At[4][16][136];     // per-wave A tile (row stride 272B, 16B aligned)
  __shared__ u16 Bh[16][136], Bl[16][136];
  int tid  = threadIdx.x;
  int wv   = tid >> 6;
  int lane = tid & 63;
  int fr = lane & 15, fg = lane >> 4;
  int row0 = blockIdx.x*64 + wv*16;

  // stage B (whole block): W2^T hi/lo [16][128]
  {
    int r = tid >> 4, c8 = (tid & 15)*8;
    *(s8v*)&Bh[r][c8] = *(const s8v*)&w2th[r*128 + c8];
    *(s8v*)&Bl[r][c8] = *(const s8v*)&w2tl[r*128 + c8];
  }
  // stage A (per wave): 16 rows x 128 bf16
  #pragma unroll
  for(int j=0;j<4;j++){
    int rl = j*4 + (lane >> 4);
    int rg = row0 + rl; if(rg >= N) rg = N-1;
    *(s8v*)&At[wv][rl][(lane & 15)*8] = *(const s8v*)&helu[(size_t)rg*128 + (lane & 15)*8];
  }
  __syncthreads();

  f4v acc = (f4v){0.f,0.f,0.f,0.f};
  #pragma unroll
  for(int kc=0; kc<4; kc++){
    int kk = kc*32 + fg*8;
    s8v a  = *(const s8v*)&At[wv][fr][kk];
    s8v bh = *(const s8v*)&Bh[fr][kk];
    s8v bl = *(const s8v*)&Bl[fr][kk];
    acc = __builtin_amdgcn_mfma_f32_16x16x32_bf16(a, bh, acc, 0,0,0);
    acc = __builtin_amdgcn_mfma_f32_16x16x32_bf16(a, bl, acc, 0,0,0);
  }
  // D layout: row = fg*4 + j, col = fr
  float asv = Asv[fr], adv = Adv[fr];
  #pragma unroll
  for(int j=0;j<4;j++){
    int row = row0 + fg*4 + j;
    float ps = acc[j]*asv, pd = acc[j]*adv;
    ps += __shfl_xor(ps,1); ps += __shfl_xor(ps,2); ps += __shfl_xor(ps,4); ps += __shfl_xor(ps,8);
    pd += __shfl_xor(pd,1); pd += __shfl_xor(pd,2); pd += __shfl_xor(pd,4); pd += __shfl_xor(pd,8);
    if(row < N){
      h2b[(size_t)row*16 + fr] = f2bu(acc[j]);
      if(fr == 0){ as2[row] = ps; ad2[row] = pd; }
    }
  }
}

// ---------------- fused layer-2 aggregation: 8 lanes/node, batched loads ----------------
__global__ __launch_bounds__(256) void k_agg2(const int* __restrict__ off,
                                              const int* __restrict__ csr,
                                              const float* __restrict__ as2,
                                              const float* __restrict__ ad2,
                                              const u32* __restrict__ h2w,
                                              const float* __restrict__ b2,
                                              float* __restrict__ outp){
  int t = threadIdx.x;
  int node = blockIdx.x*32 + (t >> 3);
  int c2 = t & 7;                        // channels 2*c2, 2*c2+1
  if(node >= N) return;
  int beg = off[node], end = off[node+1];
  float adv = ad2[node];
  float den = 0.f, num0 = 0.f, num1 = 0.f;
  int gbase = t & 56;
  for(int base = beg; base < end; base += 8){
    int cnt = end - base; if(cnt > 8) cnt = 8;
    float w_my = 0.f; int s_my = 0;
    if(c2 < cnt){
      s_my = csr[base + c2];
      float v = as2[s_my] + adv;
      v = v > 0.f ? v : NEG*v;
      w_my = __expf(v);
    }
    float ww[8]; int ss[8]; u32 uu[8];
    #pragma unroll
    for(int j=0;j<8;j++){
      ww[j] = __shfl(w_my, gbase | j);
      ss[j] = __shfl(s_my, gbase | j);
    }
    #pragma unroll
    for(int j=0;j<8;j++){
      if(j < cnt) uu[j] = h2w[(size_t)ss[j]*8 + c2];
    }
    #pragma unroll
    for(int j=0;j<8;j++){
      if(j < cnt){
        den += ww[j];
        num0 = fmaf(ww[j], blo(uu[j]), num0);
        num1 = fmaf(ww[j], bhi(uu[j]), num1);
      }
    }
  }
  float inv = 1.f / (den + 1e-16f);
  float2 bb = ((const float2*)b2)[c2];
  float2 r;
  r.x = num0*inv + bb.x;
  r.y = num1*inv + bb.y;
  ((float2*)outp)[(size_t)node*8 + c2] = r;
}

extern "C" void kernel_launch(void* const* d_in, const int* in_sizes, int n_in,
                              void* d_out, int out_size, void* d_ws, size_t ws_size,
                              hipStream_t stream){
  const float* x     = (const float*)d_in[0];
  const int*   ei    = (const int*)  d_in[1];
  const float* W1    = (const float*)d_in[2];
  const float* av_s1 = (const float*)d_in[3];
  const float* av_d1 = (const float*)d_in[4];
  const float* b1    = (const float*)d_in[5];
  const float* W2    = (const float*)d_in[6];
  const float* av_s2 = (const float*)d_in[7];
  const float* av_d2 = (const float*)d_in[8];
  const float* b2    = (const float*)d_in[9];
  float* outp = (float*)d_out;

  char* p = (char*)d_ws;
  auto alloc = [&](size_t bytes){ char* q = p; p += (bytes + 255) & ~(size_t)255; return q; };
  u16*   h1b    = (u16*)  alloc((size_t)N*HH*2);
  u16*   helu_b = (u16*)  alloc((size_t)N*HH*2);
  u16*   h2b    = (u16*)  alloc((size_t)N*CLS*2);
  float* as1    = (float*)alloc((size_t)N*HEADS*4);
  float* ad1    = (float*)alloc((size_t)N*HEADS*4);
  float* as2    = (float*)alloc((size_t)N*4);
  float* ad2    = (float*)alloc((size_t)N*4);
  int*   deg    = (int*)  alloc((size_t)N*4);
  int*   head   = (int*)  alloc((size_t)N*4);
  int*   off    = (int*)  alloc((size_t)(N+1)*4);
  int*   csr    = (int*)  alloc((size_t)ETOT*4);
  int*   srcv   = (int*)  alloc((size_t)ETOT*4);
  int*   nxt    = (int*)  alloc((size_t)ETOT*4);
  u16*   wth    = (u16*)  alloc((size_t)128*128*2);
  u16*   wtl    = (u16*)  alloc((size_t)128*128*2);
  u16*   w2th   = (u16*)  alloc((size_t)16*128*2);
  u16*   w2tl   = (u16*)  alloc((size_t)16*128*2);
  int*   bsum   = (int*)  alloc((size_t)NB*4);

  hipMemsetAsync(head, 0xFF, (size_t)N*4, stream);

  // W pre-split (W1 for gemm1, W2 for gemm2)
  k_prep<<<(128*128+255)/256, 256, 0, stream>>>(W1, W2, wth, wtl, w2th, w2tl);

  // fused: MFMA GEMM1 ∥ linked-list build
  k_gemm1link<<<GEMM_NB + LINK_NB, 256, 0, stream>>>(x, wth, wtl, h1b, ei, head, srcv, nxt);

  // fused: degree walk + block sums ∥ alpha1
  k_alphascan1<<<NB + A1_NB, 256, 0, stream>>>(h1b, av_s1, av_d1, as1, ad1, head, nxt, deg, bsum);

  // offsets (in-block boff reduce) + CSR walk-fill
  k_scan3walk<<<NB, 256, 0, stream>>>(deg, bsum, head, srcv, nxt, off, csr);

  // layer 1 aggregation
  k_agg1<<<N/4, 256, 0, stream>>>(off, csr, as1, ad1, (const u32*)h1b, b1, (u32*)helu_b);

  // layer 2
  k_gemm2m<<<(N+63)/64, 256, 0, stream>>>(helu_b, w2th, w2tl, av_s2, av_d2, h2b, as2, ad2);
  k_agg2<<<(N+31)/32, 256, 0, stream>>>(off, csr, as2, ad2, (const u32*)h2b, b2, outp);
}